// Round 1
// baseline (4278.248 us; speedup 1.0000x reference)
//
#include <hip/hip_runtime.h>

#define C_EMB 384
#define T_SEQ 256
#define B_BATCH 128
#define M_ROWS (B_BATCH * T_SEQ)   // 32768

// ---------------- LayerNorm: one block (384 threads = 6 waves) per row ----------------
__global__ __launch_bounds__(384) void ln_kernel(const float* __restrict__ x,
                                                 const float* __restrict__ g,
                                                 const float* __restrict__ bta,
                                                 float* __restrict__ out) {
    int row = blockIdx.x;
    int c = threadIdx.x;
    const float* xr = x + (size_t)row * C_EMB;
    float v = xr[c];

    __shared__ float red[6];
    float s = v;
#pragma unroll
    for (int o = 32; o; o >>= 1) s += __shfl_down(s, o);
    if ((c & 63) == 0) red[c >> 6] = s;
    __syncthreads();
    float mu = (red[0] + red[1] + red[2] + red[3] + red[4] + red[5]) * (1.0f / C_EMB);

    float d = v - mu;
    float s2 = d * d;
#pragma unroll
    for (int o = 32; o; o >>= 1) s2 += __shfl_down(s2, o);
    __syncthreads();
    if ((c & 63) == 0) red[c >> 6] = s2;
    __syncthreads();
    float var = (red[0] + red[1] + red[2] + red[3] + red[4] + red[5]) * (1.0f / C_EMB);

    out[(size_t)row * C_EMB + c] = d * rsqrtf(var + 1e-5f) * g[c] + bta[c];
}

// ---------------- Tiled fp32 GEMM: out = A[M,K] @ W[K,N] + bias (+relu) (+resid) ------
// 64x64 tile, 256 threads, 4x4 microtile, K-tile 16.
template <bool RELU, bool RESID>
__global__ __launch_bounds__(256) void gemm_kernel(const float* __restrict__ A,
                                                   const float* __restrict__ W,
                                                   const float* __restrict__ bias,
                                                   const float* __restrict__ resid,
                                                   float* __restrict__ out,
                                                   int M, int N, int K) {
    __shared__ float As[16][68];  // [k][m], padded
    __shared__ float Bs[16][68];  // [k][n], padded

    int tid = threadIdx.x;
    int tx = tid & 15, ty = tid >> 4;
    int bm = blockIdx.y * 64, bn = blockIdx.x * 64;

    float acc[4][4];
#pragma unroll
    for (int j = 0; j < 4; ++j) {
        float bv = bias[bn + tx + j * 16];
#pragma unroll
        for (int i = 0; i < 4; ++i) acc[i][j] = bv;
    }

    for (int k0 = 0; k0 < K; k0 += 16) {
#pragma unroll
        for (int i = 0; i < 4; ++i) {
            int l = tid + i * 256;
            int m = l >> 4, k = l & 15;
            As[k][m] = A[(size_t)(bm + m) * K + k0 + k];
        }
#pragma unroll
        for (int i = 0; i < 4; ++i) {
            int l = tid + i * 256;
            int k = l >> 6, n = l & 63;
            Bs[k][n] = W[(size_t)(k0 + k) * N + bn + n];
        }
        __syncthreads();
#pragma unroll
        for (int kk = 0; kk < 16; ++kk) {
            float a[4], b[4];
#pragma unroll
            for (int i = 0; i < 4; ++i) a[i] = As[kk][ty + i * 16];
#pragma unroll
            for (int j = 0; j < 4; ++j) b[j] = Bs[kk][tx + j * 16];
#pragma unroll
            for (int i = 0; i < 4; ++i)
#pragma unroll
                for (int j = 0; j < 4; ++j) acc[i][j] += a[i] * b[j];
        }
        __syncthreads();
    }

#pragma unroll
    for (int i = 0; i < 4; ++i) {
        int m = bm + ty + i * 16;
#pragma unroll
        for (int j = 0; j < 4; ++j) {
            int n = bn + tx + j * 16;
            float v = acc[i][j];
            if (RELU) v = fmaxf(v, 0.0f);
            if (RESID) v += resid[(size_t)m * N + n];
            out[(size_t)m * N + n] = v;
        }
    }
}

// ---------------- Causal attention: one block (256 threads) per (b, t) ----------------
// qkv row layout: [q(384) | k(384) | v(384)], row = b*T + s
__global__ __launch_bounds__(256) void attn_kernel(const float* __restrict__ qkv,
                                                   float* __restrict__ y) {
    int t = blockIdx.x, b = blockIdx.y;
    int tid = threadIdx.x;
    const float* base = qkv + (size_t)b * T_SEQ * 1152;

    __shared__ float qs[C_EMB];
    __shared__ float ps[T_SEQ];
    __shared__ float red[4];

    const float* qrow = base + (size_t)t * 1152;
    for (int c = tid; c < C_EMB; c += 256) qs[c] = qrow[c];
    __syncthreads();

    float score = -INFINITY;
    if (tid <= t) {
        const float* krow = base + (size_t)tid * 1152 + 384;
        float d = 0.0f;
#pragma unroll 4
        for (int c = 0; c < C_EMB; ++c) d += qs[c] * krow[c];
        score = d * 0.05103103630798288f;  // 1/sqrt(384)
    }

    // block max
    float mx = score;
#pragma unroll
    for (int o = 32; o; o >>= 1) mx = fmaxf(mx, __shfl_down(mx, o));
    if ((tid & 63) == 0) red[tid >> 6] = mx;
    __syncthreads();
    mx = fmaxf(fmaxf(red[0], red[1]), fmaxf(red[2], red[3]));

    float p = (tid <= t) ? __expf(score - mx) : 0.0f;

    // block sum
    float sm = p;
#pragma unroll
    for (int o = 32; o; o >>= 1) sm += __shfl_down(sm, o);
    __syncthreads();
    if ((tid & 63) == 0) red[tid >> 6] = sm;
    __syncthreads();
    sm = red[0] + red[1] + red[2] + red[3];

    ps[tid] = p / sm;
    __syncthreads();

    float* yrow = y + (size_t)(b * T_SEQ + t) * C_EMB;
    for (int c = tid; c < C_EMB; c += 256) {
        float acc = 0.0f;
        const float* vcol = base + 768 + c;
        for (int s = 0; s <= t; ++s) acc += ps[s] * vcol[(size_t)s * 1152];
        yrow[c] = acc;
    }
}

extern "C" void kernel_launch(void* const* d_in, const int* in_sizes, int n_in,
                              void* d_out, int out_size, void* d_ws, size_t ws_size,
                              hipStream_t stream) {
    const float* x      = (const float*)d_in[0];
    const float* W_attn = (const float*)d_in[1];
    const float* b_attn = (const float*)d_in[2];
    const float* W_proj = (const float*)d_in[3];
    const float* b_proj = (const float*)d_in[4];
    const float* ln1_g  = (const float*)d_in[5];
    const float* ln1_b  = (const float*)d_in[6];
    const float* ln2_g  = (const float*)d_in[7];
    const float* ln2_b  = (const float*)d_in[8];
    const float* W1     = (const float*)d_in[9];
    const float* b1     = (const float*)d_in[10];
    const float* W2     = (const float*)d_in[11];
    const float* b2     = (const float*)d_in[12];
    float* out = (float*)d_out;
    float* ws  = (float*)d_ws;

    const size_t H_ELEMS   = (size_t)M_ROWS * C_EMB;       // 12,582,912
    const size_t QKV_ELEMS = (size_t)M_ROWS * 3 * C_EMB;   // 37,748,736

    float* h   = ws;                       // [M, 384]   (later reused as h2)
    float* qkv = ws + H_ELEMS;             // [M, 1152]
    float* yb  = ws + H_ELEMS + QKV_ELEMS; // [M, 384]
    float* ff  = ws + H_ELEMS;             // [M, 1536]  reuses qkv+yb after attention

    // 1. h = LN1(x)
    ln_kernel<<<M_ROWS, 384, 0, stream>>>(x, ln1_g, ln1_b, h);
    // 2. qkv = h @ W_attn + b_attn
    gemm_kernel<false, false><<<dim3(1152 / 64, M_ROWS / 64), 256, 0, stream>>>(
        h, W_attn, b_attn, nullptr, qkv, M_ROWS, 1152, C_EMB);
    // 3. yb = causal_attention(qkv)
    attn_kernel<<<dim3(T_SEQ, B_BATCH), 256, 0, stream>>>(qkv, yb);
    // 4. out = x + yb @ W_proj + b_proj
    gemm_kernel<false, true><<<dim3(C_EMB / 64, M_ROWS / 64), 256, 0, stream>>>(
        yb, W_proj, b_proj, x, out, M_ROWS, C_EMB, C_EMB);
    // 5. h2 = LN2(out)   (reuse h)
    ln_kernel<<<M_ROWS, 384, 0, stream>>>(out, ln2_g, ln2_b, h);

    // 6/7. MLP, chunked over rows if ws can't hold full [M,1536] ff buffer
    size_t avail = ws_size / sizeof(float) - H_ELEMS;
    size_t ff_need = (size_t)M_ROWS * 1536;
    int rows_per_chunk;
    if (avail >= ff_need) {
        rows_per_chunk = M_ROWS;
    } else {
        rows_per_chunk = (int)((avail / 1536) / 64) * 64;
        if (rows_per_chunk < 64) rows_per_chunk = 64;  // last-resort; ws assumed >= ~1MB
    }
    for (int r0 = 0; r0 < M_ROWS; r0 += rows_per_chunk) {
        int rows = (M_ROWS - r0 < rows_per_chunk) ? (M_ROWS - r0) : rows_per_chunk;
        const float* h2c = h + (size_t)r0 * C_EMB;
        float* outc = out + (size_t)r0 * C_EMB;
        // ff = relu(h2 @ W1 + b1)
        gemm_kernel<true, false><<<dim3(1536 / 64, rows / 64), 256, 0, stream>>>(
            h2c, W1, b1, nullptr, ff, rows, 1536, C_EMB);
        // out += ff @ W2 + b2
        gemm_kernel<false, true><<<dim3(C_EMB / 64, rows / 64), 256, 0, stream>>>(
            ff, W2, b2, outc, outc, rows, C_EMB, 1536);
    }
}

// Round 2
// 2520.829 us; speedup vs baseline: 1.6972x; 1.6972x over previous
//
#include <hip/hip_runtime.h>

#define C_EMB 384
#define T_SEQ 256
#define B_BATCH 128
#define M_ROWS (B_BATCH * T_SEQ)   // 32768
#define QKV_LD 1152                // row stride of qkv buffer

// ---------------- LayerNorm: one block (384 threads = 6 waves) per row ----------------
__global__ __launch_bounds__(384) void ln_kernel(const float* __restrict__ x,
                                                 const float* __restrict__ g,
                                                 const float* __restrict__ bta,
                                                 float* __restrict__ out) {
    int row = blockIdx.x;
    int c = threadIdx.x;
    const float* xr = x + (size_t)row * C_EMB;
    float v = xr[c];

    __shared__ float red[6];
    float s = v;
#pragma unroll
    for (int o = 32; o; o >>= 1) s += __shfl_down(s, o);
    if ((c & 63) == 0) red[c >> 6] = s;
    __syncthreads();
    float mu = (red[0] + red[1] + red[2] + red[3] + red[4] + red[5]) * (1.0f / C_EMB);

    float d = v - mu;
    float s2 = d * d;
#pragma unroll
    for (int o = 32; o; o >>= 1) s2 += __shfl_down(s2, o);
    __syncthreads();
    if ((c & 63) == 0) red[c >> 6] = s2;
    __syncthreads();
    float var = (red[0] + red[1] + red[2] + red[3] + red[4] + red[5]) * (1.0f / C_EMB);

    out[(size_t)row * C_EMB + c] = d * rsqrtf(var + 1e-5f) * g[c] + bta[c];
}

// ---------------- Tiled fp32 GEMM: out = A[M,K] @ W[K,N] + bias (+relu) (+resid) ------
template <bool RELU, bool RESID>
__global__ __launch_bounds__(256) void gemm_kernel(const float* __restrict__ A,
                                                   const float* __restrict__ W,
                                                   const float* __restrict__ bias,
                                                   const float* __restrict__ resid,
                                                   float* __restrict__ out,
                                                   int M, int N, int K) {
    __shared__ float As[16][68];  // [k][m], padded
    __shared__ float Bs[16][68];  // [k][n], padded

    int tid = threadIdx.x;
    int tx = tid & 15, ty = tid >> 4;
    int bm = blockIdx.y * 64, bn = blockIdx.x * 64;

    float acc[4][4];
#pragma unroll
    for (int j = 0; j < 4; ++j) {
        float bv = bias[bn + tx + j * 16];
#pragma unroll
        for (int i = 0; i < 4; ++i) acc[i][j] = bv;
    }

    for (int k0 = 0; k0 < K; k0 += 16) {
#pragma unroll
        for (int i = 0; i < 4; ++i) {
            int l = tid + i * 256;
            int m = l >> 4, k = l & 15;
            As[k][m] = A[(size_t)(bm + m) * K + k0 + k];
        }
#pragma unroll
        for (int i = 0; i < 4; ++i) {
            int l = tid + i * 256;
            int k = l >> 6, n = l & 63;
            Bs[k][n] = W[(size_t)(k0 + k) * N + bn + n];
        }
        __syncthreads();
#pragma unroll
        for (int kk = 0; kk < 16; ++kk) {
            float a[4], b[4];
#pragma unroll
            for (int i = 0; i < 4; ++i) a[i] = As[kk][ty + i * 16];
#pragma unroll
            for (int j = 0; j < 4; ++j) b[j] = Bs[kk][tx + j * 16];
#pragma unroll
            for (int i = 0; i < 4; ++i)
#pragma unroll
                for (int j = 0; j < 4; ++j) acc[i][j] += a[i] * b[j];
        }
        __syncthreads();
    }

#pragma unroll
    for (int i = 0; i < 4; ++i) {
        int m = bm + ty + i * 16;
#pragma unroll
        for (int j = 0; j < 4; ++j) {
            int n = bn + tx + j * 16;
            float v = acc[i][j];
            if (RELU) v = fmaxf(v, 0.0f);
            if (RESID) v += resid[(size_t)m * N + n];
            out[(size_t)m * N + n] = v;
        }
    }
}

// ---------------- Attention pass 1: S = scale * Q @ K^T, lower-triangle tiles only ----
// Q row m: qkv[b][m][0..383]; K row n: qkv[b][n][384..767]. S is [B][T][T].
__global__ __launch_bounds__(256) void qk_kernel(const float* __restrict__ qkv,
                                                 float* __restrict__ S) {
    static const int TM[10] = {0, 1, 1, 2, 2, 2, 3, 3, 3, 3};
    static const int TN[10] = {0, 0, 1, 0, 1, 2, 0, 1, 2, 3};
    int b = blockIdx.y;
    int bm = TM[blockIdx.x] * 64;  // query tile base
    int bn = TN[blockIdx.x] * 64;  // key tile base
    const float* base = qkv + (size_t)b * T_SEQ * QKV_LD;

    __shared__ float As[16][68];  // [k][m] : Q fragment
    __shared__ float Bs[16][68];  // [k][n] : K fragment

    int tid = threadIdx.x;
    int tx = tid & 15, ty = tid >> 4;

    float acc[4][4];
#pragma unroll
    for (int i = 0; i < 4; ++i)
#pragma unroll
        for (int j = 0; j < 4; ++j) acc[i][j] = 0.0f;

    for (int k0 = 0; k0 < C_EMB; k0 += 16) {
#pragma unroll
        for (int i = 0; i < 4; ++i) {
            int l = tid + i * 256;
            int m = l >> 4, k = l & 15;
            As[k][m] = base[(size_t)(bm + m) * QKV_LD + k0 + k];         // Q
            Bs[k][m] = base[(size_t)(bn + m) * QKV_LD + 384 + k0 + k];   // K
        }
        __syncthreads();
#pragma unroll
        for (int kk = 0; kk < 16; ++kk) {
            float a[4], bb[4];
#pragma unroll
            for (int i = 0; i < 4; ++i) a[i] = As[kk][ty + i * 16];
#pragma unroll
            for (int j = 0; j < 4; ++j) bb[j] = Bs[kk][tx + j * 16];
#pragma unroll
            for (int i = 0; i < 4; ++i)
#pragma unroll
                for (int j = 0; j < 4; ++j) acc[i][j] += a[i] * bb[j];
        }
        __syncthreads();
    }

    float* Sb = S + (size_t)b * T_SEQ * T_SEQ;
#pragma unroll
    for (int i = 0; i < 4; ++i) {
        int m = bm + ty + i * 16;
#pragma unroll
        for (int j = 0; j < 4; ++j) {
            int n = bn + tx + j * 16;
            Sb[(size_t)m * T_SEQ + n] = acc[i][j] * 0.05103103630798288f;  // 1/sqrt(384)
        }
    }
    // entries with n > m (within diagonal tiles) hold garbage; softmax never reads them.
}

// ---------------- Attention pass 2: causal softmax over S rows ------------------------
// One block per row (b*T + t); 256 threads, one score each. Writes P (zeros for s > t).
__global__ __launch_bounds__(256) void softmax_kernel(float* __restrict__ S) {
    int row = blockIdx.x;          // = b*T + t
    int t = row & (T_SEQ - 1);
    int tid = threadIdx.x;
    float* Sr = S + (size_t)row * T_SEQ;

    __shared__ float red[4];
    float sc = (tid <= t) ? Sr[tid] : -INFINITY;

    float mx = sc;
#pragma unroll
    for (int o = 32; o; o >>= 1) mx = fmaxf(mx, __shfl_down(mx, o));
    if ((tid & 63) == 0) red[tid >> 6] = mx;
    __syncthreads();
    mx = fmaxf(fmaxf(red[0], red[1]), fmaxf(red[2], red[3]));

    float p = (tid <= t) ? __expf(sc - mx) : 0.0f;
    float sm = p;
#pragma unroll
    for (int o = 32; o; o >>= 1) sm += __shfl_down(sm, o);
    __syncthreads();
    if ((tid & 63) == 0) red[tid >> 6] = sm;
    __syncthreads();
    sm = red[0] + red[1] + red[2] + red[3];

    Sr[tid] = p / sm;
}

// ---------------- Attention pass 3: y = P @ V (causal k-tile skipping) ----------------
// P [T,T] contiguous; V row s: qkv[b][s][768..1151]. y is [B*T, 384].
__global__ __launch_bounds__(256) void pv_kernel(const float* __restrict__ P,
                                                 const float* __restrict__ qkv,
                                                 float* __restrict__ y) {
    int b = blockIdx.z;
    int bm = blockIdx.y * 64;   // query tile base
    int bn = blockIdx.x * 64;   // channel tile base
    const float* Pb = P + (size_t)b * T_SEQ * T_SEQ;
    const float* base = qkv + (size_t)b * T_SEQ * QKV_LD;

    __shared__ float As[16][68];  // [k][m] : P fragment
    __shared__ float Bs[16][68];  // [k][n] : V fragment

    int tid = threadIdx.x;
    int tx = tid & 15, ty = tid >> 4;

    float acc[4][4];
#pragma unroll
    for (int i = 0; i < 4; ++i)
#pragma unroll
        for (int j = 0; j < 4; ++j) acc[i][j] = 0.0f;

    int kmax = bm + 64;  // rows in this m-tile attend to s <= bm+63
    for (int k0 = 0; k0 < kmax; k0 += 16) {
#pragma unroll
        for (int i = 0; i < 4; ++i) {
            int l = tid + i * 256;
            int m = l >> 4, k = l & 15;
            As[k][m] = Pb[(size_t)(bm + m) * T_SEQ + k0 + k];
        }
#pragma unroll
        for (int i = 0; i < 4; ++i) {
            int l = tid + i * 256;
            int k = l >> 6, n = l & 63;
            Bs[k][n] = base[(size_t)(k0 + k) * QKV_LD + 768 + bn + n];
        }
        __syncthreads();
#pragma unroll
        for (int kk = 0; kk < 16; ++kk) {
            float a[4], bb[4];
#pragma unroll
            for (int i = 0; i < 4; ++i) a[i] = As[kk][ty + i * 16];
#pragma unroll
            for (int j = 0; j < 4; ++j) bb[j] = Bs[kk][tx + j * 16];
#pragma unroll
            for (int i = 0; i < 4; ++i)
#pragma unroll
                for (int j = 0; j < 4; ++j) acc[i][j] += a[i] * bb[j];
        }
        __syncthreads();
    }

#pragma unroll
    for (int i = 0; i < 4; ++i) {
        int m = bm + ty + i * 16;
#pragma unroll
        for (int j = 0; j < 4; ++j) {
            int n = bn + tx + j * 16;
            y[((size_t)b * T_SEQ + m) * C_EMB + n] = acc[i][j];
        }
    }
}

extern "C" void kernel_launch(void* const* d_in, const int* in_sizes, int n_in,
                              void* d_out, int out_size, void* d_ws, size_t ws_size,
                              hipStream_t stream) {
    const float* x      = (const float*)d_in[0];
    const float* W_attn = (const float*)d_in[1];
    const float* b_attn = (const float*)d_in[2];
    const float* W_proj = (const float*)d_in[3];
    const float* b_proj = (const float*)d_in[4];
    const float* ln1_g  = (const float*)d_in[5];
    const float* ln1_b  = (const float*)d_in[6];
    const float* ln2_g  = (const float*)d_in[7];
    const float* ln2_b  = (const float*)d_in[8];
    const float* W1     = (const float*)d_in[9];
    const float* b1     = (const float*)d_in[10];
    const float* W2     = (const float*)d_in[11];
    const float* b2     = (const float*)d_in[12];
    float* out = (float*)d_out;
    float* ws  = (float*)d_ws;

    const size_t H_ELEMS   = (size_t)M_ROWS * C_EMB;       // 12,582,912
    const size_t QKV_ELEMS = (size_t)M_ROWS * 3 * C_EMB;   // 37,748,736

    float* h   = ws;                       // [M, 384]  (LN out; later: S alias, then h2)
    float* qkv = ws + H_ELEMS;             // [M, 1152]
    float* yb  = ws + H_ELEMS + QKV_ELEMS; // [M, 384]
    float* S   = ws;                       // [B, T, T] = 8.39M floats, aliases dead h
    float* ff  = ws + H_ELEMS;             // [M, 1536]  reuses qkv+yb after attention

    // 1. h = LN1(x)
    ln_kernel<<<M_ROWS, 384, 0, stream>>>(x, ln1_g, ln1_b, h);
    // 2. qkv = h @ W_attn + b_attn   (h dead afterwards)
    gemm_kernel<false, false><<<dim3(1152 / 64, M_ROWS / 64), 256, 0, stream>>>(
        h, W_attn, b_attn, nullptr, qkv, M_ROWS, 1152, C_EMB);
    // 3a. S = scale * Q@K^T (lower-triangle tiles)
    qk_kernel<<<dim3(10, B_BATCH), 256, 0, stream>>>(qkv, S);
    // 3b. P = causal softmax(S), in place
    softmax_kernel<<<M_ROWS, 256, 0, stream>>>(S);
    // 3c. yb = P @ V
    pv_kernel<<<dim3(C_EMB / 64, T_SEQ / 64, B_BATCH), 256, 0, stream>>>(S, qkv, yb);
    // 4. out = x + yb @ W_proj + b_proj
    gemm_kernel<false, true><<<dim3(C_EMB / 64, M_ROWS / 64), 256, 0, stream>>>(
        yb, W_proj, b_proj, x, out, M_ROWS, C_EMB, C_EMB);
    // 5. h2 = LN2(out)   (reuse h region — S is dead now)
    ln_kernel<<<M_ROWS, 384, 0, stream>>>(out, ln2_g, ln2_b, h);

    // 6/7. MLP, chunked over rows if ws can't hold full [M,1536] ff buffer
    size_t avail = ws_size / sizeof(float) - H_ELEMS;
    size_t ff_need = (size_t)M_ROWS * 1536;
    int rows_per_chunk;
    if (avail >= ff_need) {
        rows_per_chunk = M_ROWS;
    } else {
        rows_per_chunk = (int)((avail / 1536) / 64) * 64;
        if (rows_per_chunk < 64) rows_per_chunk = 64;
    }
    for (int r0 = 0; r0 < M_ROWS; r0 += rows_per_chunk) {
        int rows = (M_ROWS - r0 < rows_per_chunk) ? (M_ROWS - r0) : rows_per_chunk;
        const float* h2c = h + (size_t)r0 * C_EMB;
        float* outc = out + (size_t)r0 * C_EMB;
        gemm_kernel<true, false><<<dim3(1536 / 64, rows / 64), 256, 0, stream>>>(
            h2c, W1, b1, nullptr, ff, rows, 1536, C_EMB);
        gemm_kernel<false, true><<<dim3(C_EMB / 64, rows / 64), 256, 0, stream>>>(
            ff, W2, b2, outc, outc, rows, C_EMB, 1536);
    }
}

// Round 4
// 688.832 us; speedup vs baseline: 6.2109x; 3.6596x over previous
//
#include <hip/hip_runtime.h>
#include <hip/hip_bf16.h>

#define C_EMB 384
#define T_SEQ 256
#define B_BATCH 128
#define M_ROWS (B_BATCH * T_SEQ)   // 32768
#define QKV_LD 1152                // row stride of qkv buffer (fp32)

typedef __bf16 bf16_8 __attribute__((ext_vector_type(8)));
typedef float f32x4 __attribute__((ext_vector_type(4)));

// ---------------- Weight cast + transpose: Wt[n][k] = bf16(W[k][n]) ------------------
__global__ __launch_bounds__(256) void cast_transpose_kernel(const float* __restrict__ W,
                                                             __bf16* __restrict__ Wt,
                                                             int K, int N) {
    __shared__ float t[32][33];
    int k0 = blockIdx.y * 32, n0 = blockIdx.x * 32;
    int tx = threadIdx.x & 31, ty = threadIdx.x >> 5;  // ty: 0..7
#pragma unroll
    for (int i = 0; i < 4; ++i)
        t[ty + i * 8][tx] = W[(size_t)(k0 + ty + i * 8) * N + n0 + tx];
    __syncthreads();
#pragma unroll
    for (int i = 0; i < 4; ++i) {
        int n = ty + i * 8;
        Wt[(size_t)(n0 + n) * K + k0 + tx] = (__bf16)t[tx][n];
    }
}

// ---------------- LayerNorm: one block (384 threads) per row, bf16 out ----------------
__global__ __launch_bounds__(384) void ln_kernel(const float* __restrict__ x,
                                                 const float* __restrict__ g,
                                                 const float* __restrict__ bta,
                                                 __bf16* __restrict__ out) {
    int row = blockIdx.x;
    int c = threadIdx.x;
    float v = x[(size_t)row * C_EMB + c];

    __shared__ float red[6];
    float s = v;
#pragma unroll
    for (int o = 32; o; o >>= 1) s += __shfl_down(s, o);
    if ((c & 63) == 0) red[c >> 6] = s;
    __syncthreads();
    float mu = (red[0] + red[1] + red[2] + red[3] + red[4] + red[5]) * (1.0f / C_EMB);

    float d = v - mu;
    float s2 = d * d;
#pragma unroll
    for (int o = 32; o; o >>= 1) s2 += __shfl_down(s2, o);
    __syncthreads();
    if ((c & 63) == 0) red[c >> 6] = s2;
    __syncthreads();
    float var = (red[0] + red[1] + red[2] + red[3] + red[4] + red[5]) * (1.0f / C_EMB);

    out[(size_t)row * C_EMB + c] = (__bf16)(d * rsqrtf(var + 1e-5f) * g[c] + bta[c]);
}

// ---------------- bf16 MFMA GEMM: out = A[M,K] @ Bt[N,K]^T + bias (+relu)(+resid) -----
// 128x128 tile, 256 thr = 2x2 waves, each wave 4x4 of 16x16x32 mfma. BK=32.
// LDS row stride 40 bf16 (80 B): frag reads land 2-way max on banks (free per m136).
// __align__(16): staging uses 16-B ds_write_b128/ds_read_b128 — alignment must be
// guaranteed, not accidental (suspected cause of round-3 device abort).
#define BK 32
#define LDSS 40

template <bool RELU, bool RESID, bool OUT_BF16>
__global__ __launch_bounds__(256) void mfma_gemm(const __bf16* __restrict__ A,
                                                 const __bf16* __restrict__ Bt,
                                                 const float* __restrict__ bias,
                                                 const float* __restrict__ resid,
                                                 void* __restrict__ out_,
                                                 int M, int N, int K) {
    __shared__ __align__(16) __bf16 As[128 * LDSS];
    __shared__ __align__(16) __bf16 Bs[128 * LDSS];

    int tid = threadIdx.x;
    int wave = tid >> 6, lane = tid & 63;
    int wr = wave >> 1, wc = wave & 1;   // wave's 64x64 quadrant
    int quad = lane >> 4, l16 = lane & 15;
    int bm = blockIdx.y * 128, bn = blockIdx.x * 128;

    f32x4 acc[4][4] = {};

    // staging decomposition: 512 chunks of 8 bf16 per tile; 2 chunks/thread
    int c0 = tid, c1 = tid + 256;
    int ra0 = c0 >> 2, ka0 = (c0 & 3) * 8;
    int ra1 = c1 >> 2, ka1 = (c1 & 3) * 8;

    for (int k0 = 0; k0 < K; k0 += BK) {
        const __bf16* Ab = A + (size_t)bm * K + k0;
        const __bf16* Bb = Bt + (size_t)bn * K + k0;
        float4 a0 = *reinterpret_cast<const float4*>(Ab + (size_t)ra0 * K + ka0);
        float4 a1 = *reinterpret_cast<const float4*>(Ab + (size_t)ra1 * K + ka1);
        float4 b0 = *reinterpret_cast<const float4*>(Bb + (size_t)ra0 * K + ka0);
        float4 b1 = *reinterpret_cast<const float4*>(Bb + (size_t)ra1 * K + ka1);
        *reinterpret_cast<float4*>(&As[ra0 * LDSS + ka0]) = a0;
        *reinterpret_cast<float4*>(&As[ra1 * LDSS + ka1]) = a1;
        *reinterpret_cast<float4*>(&Bs[ra0 * LDSS + ka0]) = b0;
        *reinterpret_cast<float4*>(&Bs[ra1 * LDSS + ka1]) = b1;
        __syncthreads();

        bf16_8 af[4], bf[4];
#pragma unroll
        for (int i = 0; i < 4; ++i)
            af[i] = *reinterpret_cast<const bf16_8*>(&As[(wr * 64 + i * 16 + l16) * LDSS + quad * 8]);
#pragma unroll
        for (int j = 0; j < 4; ++j)
            bf[j] = *reinterpret_cast<const bf16_8*>(&Bs[(wc * 64 + j * 16 + l16) * LDSS + quad * 8]);
#pragma unroll
        for (int i = 0; i < 4; ++i)
#pragma unroll
            for (int j = 0; j < 4; ++j)
                acc[i][j] = __builtin_amdgcn_mfma_f32_16x16x32_bf16(af[i], bf[j], acc[i][j], 0, 0, 0);
        __syncthreads();
    }

    // epilogue: C/D layout col = lane&15, row = quad*4 + r  [m89-verified]
#pragma unroll
    for (int i = 0; i < 4; ++i) {
#pragma unroll
        for (int r = 0; r < 4; ++r) {
            int m = bm + wr * 64 + i * 16 + quad * 4 + r;
#pragma unroll
            for (int j = 0; j < 4; ++j) {
                int n = bn + wc * 64 + j * 16 + l16;
                float v = acc[i][j][r] + bias[n];
                if (RELU) v = fmaxf(v, 0.0f);
                if (RESID) v += resid[(size_t)m * N + n];
                if (OUT_BF16)
                    ((__bf16*)out_)[(size_t)m * N + n] = (__bf16)v;
                else
                    ((float*)out_)[(size_t)m * N + n] = v;
            }
        }
    }
}

// ---------------- Attention pass 1: S = scale * Q @ K^T, lower-triangle tiles ---------
__global__ __launch_bounds__(256) void qk_kernel(const float* __restrict__ qkv,
                                                 float* __restrict__ S) {
    static const int TM[10] = {0, 1, 1, 2, 2, 2, 3, 3, 3, 3};
    static const int TN[10] = {0, 0, 1, 0, 1, 2, 0, 1, 2, 3};
    int b = blockIdx.y;
    int bm = TM[blockIdx.x] * 64;
    int bn = TN[blockIdx.x] * 64;
    const float* base = qkv + (size_t)b * T_SEQ * QKV_LD;

    __shared__ float Asq[16][68];
    __shared__ float Bsq[16][68];

    int tid = threadIdx.x;
    int tx = tid & 15, ty = tid >> 4;

    float acc[4][4];
#pragma unroll
    for (int i = 0; i < 4; ++i)
#pragma unroll
        for (int j = 0; j < 4; ++j) acc[i][j] = 0.0f;

    for (int k0 = 0; k0 < C_EMB; k0 += 16) {
#pragma unroll
        for (int i = 0; i < 4; ++i) {
            int l = tid + i * 256;
            int m = l >> 4, k = l & 15;
            Asq[k][m] = base[(size_t)(bm + m) * QKV_LD + k0 + k];
            Bsq[k][m] = base[(size_t)(bn + m) * QKV_LD + 384 + k0 + k];
        }
        __syncthreads();
#pragma unroll
        for (int kk = 0; kk < 16; ++kk) {
            float a[4], bb[4];
#pragma unroll
            for (int i = 0; i < 4; ++i) a[i] = Asq[kk][ty + i * 16];
#pragma unroll
            for (int j = 0; j < 4; ++j) bb[j] = Bsq[kk][tx + j * 16];
#pragma unroll
            for (int i = 0; i < 4; ++i)
#pragma unroll
                for (int j = 0; j < 4; ++j) acc[i][j] += a[i] * bb[j];
        }
        __syncthreads();
    }

    float* Sb = S + (size_t)b * T_SEQ * T_SEQ;
#pragma unroll
    for (int i = 0; i < 4; ++i) {
        int m = bm + ty + i * 16;
#pragma unroll
        for (int j = 0; j < 4; ++j) {
            int n = bn + tx + j * 16;
            Sb[(size_t)m * T_SEQ + n] = acc[i][j] * 0.05103103630798288f;
        }
    }
}

// ---------------- Attention pass 2: causal softmax -----------------------------------
__global__ __launch_bounds__(256) void softmax_kernel(float* __restrict__ S) {
    int row = blockIdx.x;
    int t = row & (T_SEQ - 1);
    int tid = threadIdx.x;
    float* Sr = S + (size_t)row * T_SEQ;

    __shared__ float red[4];
    float sc = (tid <= t) ? Sr[tid] : -INFINITY;

    float mx = sc;
#pragma unroll
    for (int o = 32; o; o >>= 1) mx = fmaxf(mx, __shfl_down(mx, o));
    if ((tid & 63) == 0) red[tid >> 6] = mx;
    __syncthreads();
    mx = fmaxf(fmaxf(red[0], red[1]), fmaxf(red[2], red[3]));

    float p = (tid <= t) ? __expf(sc - mx) : 0.0f;
    float sm = p;
#pragma unroll
    for (int o = 32; o; o >>= 1) sm += __shfl_down(sm, o);
    __syncthreads();
    if ((tid & 63) == 0) red[tid >> 6] = sm;
    __syncthreads();
    sm = red[0] + red[1] + red[2] + red[3];

    Sr[tid] = p / sm;
}

// ---------------- Attention pass 3: y = P @ V (bf16 out) ------------------------------
__global__ __launch_bounds__(256) void pv_kernel(const float* __restrict__ P,
                                                 const float* __restrict__ qkv,
                                                 __bf16* __restrict__ y) {
    int b = blockIdx.z;
    int bm = blockIdx.y * 64;
    int bn = blockIdx.x * 64;
    const float* Pb = P + (size_t)b * T_SEQ * T_SEQ;
    const float* base = qkv + (size_t)b * T_SEQ * QKV_LD;

    __shared__ float Asq[16][68];
    __shared__ float Bsq[16][68];

    int tid = threadIdx.x;
    int tx = tid & 15, ty = tid >> 4;

    float acc[4][4];
#pragma unroll
    for (int i = 0; i < 4; ++i)
#pragma unroll
        for (int j = 0; j < 4; ++j) acc[i][j] = 0.0f;

    int kmax = bm + 64;
    for (int k0 = 0; k0 < kmax; k0 += 16) {
#pragma unroll
        for (int i = 0; i < 4; ++i) {
            int l = tid + i * 256;
            int m = l >> 4, k = l & 15;
            Asq[k][m] = Pb[(size_t)(bm + m) * T_SEQ + k0 + k];
        }
#pragma unroll
        for (int i = 0; i < 4; ++i) {
            int l = tid + i * 256;
            int k = l >> 6, n = l & 63;
            Bsq[k][n] = base[(size_t)(k0 + k) * QKV_LD + 768 + bn + n];
        }
        __syncthreads();
#pragma unroll
        for (int kk = 0; kk < 16; ++kk) {
            float a[4], bb[4];
#pragma unroll
            for (int i = 0; i < 4; ++i) a[i] = Asq[kk][ty + i * 16];
#pragma unroll
            for (int j = 0; j < 4; ++j) bb[j] = Bsq[kk][tx + j * 16];
#pragma unroll
            for (int i = 0; i < 4; ++i)
#pragma unroll
                for (int j = 0; j < 4; ++j) acc[i][j] += a[i] * bb[j];
        }
        __syncthreads();
    }

#pragma unroll
    for (int i = 0; i < 4; ++i) {
        int m = bm + ty + i * 16;
#pragma unroll
        for (int j = 0; j < 4; ++j) {
            int n = bn + tx + j * 16;
            y[((size_t)b * T_SEQ + m) * C_EMB + n] = (__bf16)acc[i][j];
        }
    }
}

extern "C" void kernel_launch(void* const* d_in, const int* in_sizes, int n_in,
                              void* d_out, int out_size, void* d_ws, size_t ws_size,
                              hipStream_t stream) {
    const float* x      = (const float*)d_in[0];
    const float* W_attn = (const float*)d_in[1];
    const float* b_attn = (const float*)d_in[2];
    const float* W_proj = (const float*)d_in[3];
    const float* b_proj = (const float*)d_in[4];
    const float* ln1_g  = (const float*)d_in[5];
    const float* ln1_b  = (const float*)d_in[6];
    const float* ln2_g  = (const float*)d_in[7];
    const float* ln2_b  = (const float*)d_in[8];
    const float* W1     = (const float*)d_in[9];
    const float* b1     = (const float*)d_in[10];
    const float* W2     = (const float*)d_in[11];
    const float* b2     = (const float*)d_in[12];
    float* out = (float*)d_out;

    // ---- workspace layout (238.4 MB total): Wt's | h | yb | qkv | S ; ff aliases qkv
    __bf16* Wattn_t = (__bf16*)d_ws;                            // [1152,384]
    __bf16* Wproj_t = Wattn_t + (size_t)1152 * 384;             // [384,384]
    __bf16* W1_t    = Wproj_t + (size_t)384 * 384;              // [1536,384]
    __bf16* W2_t    = W1_t + (size_t)1536 * 384;                // [384,1536]
    __bf16* h       = W2_t + (size_t)384 * 1536;                // [M,384] bf16 (h, later h2)
    __bf16* yb      = h + (size_t)M_ROWS * 384;                 // [M,384] bf16
    float*  qkv     = (float*)(yb + (size_t)M_ROWS * 384);      // [M,1152] fp32
    float*  S       = qkv + (size_t)M_ROWS * QKV_LD;            // [B,T,T] fp32
    __bf16* ff      = (__bf16*)qkv;                             // [M,1536] bf16, aliases dead qkv

    // 0. weights → bf16, transposed to [N,K]
    cast_transpose_kernel<<<dim3(1152 / 32, 384 / 32), 256, 0, stream>>>(W_attn, Wattn_t, 384, 1152);
    cast_transpose_kernel<<<dim3(384 / 32, 384 / 32), 256, 0, stream>>>(W_proj, Wproj_t, 384, 384);
    cast_transpose_kernel<<<dim3(1536 / 32, 384 / 32), 256, 0, stream>>>(W1, W1_t, 384, 1536);
    cast_transpose_kernel<<<dim3(384 / 32, 1536 / 32), 256, 0, stream>>>(W2, W2_t, 1536, 384);

    // 1. h = bf16(LN1(x))
    ln_kernel<<<M_ROWS, 384, 0, stream>>>(x, ln1_g, ln1_b, h);
    // 2. qkv = h @ W_attn + b_attn  (fp32 out)
    mfma_gemm<false, false, false><<<dim3(1152 / 128, M_ROWS / 128), 256, 0, stream>>>(
        h, Wattn_t, b_attn, nullptr, qkv, M_ROWS, 1152, 384);
    // 3. attention (fp32 core)
    qk_kernel<<<dim3(10, B_BATCH), 256, 0, stream>>>(qkv, S);
    softmax_kernel<<<M_ROWS, 256, 0, stream>>>(S);
    pv_kernel<<<dim3(C_EMB / 64, T_SEQ / 64, B_BATCH), 256, 0, stream>>>(S, qkv, yb);
    // 4. out = x + yb @ W_proj + b_proj
    mfma_gemm<false, true, false><<<dim3(384 / 128, M_ROWS / 128), 256, 0, stream>>>(
        yb, Wproj_t, b_proj, x, out, M_ROWS, 384, 384);
    // 5. h2 = bf16(LN2(out))
    ln_kernel<<<M_ROWS, 384, 0, stream>>>(out, ln2_g, ln2_b, h);
    // 6. ff = bf16(relu(h2 @ W1 + b1))
    mfma_gemm<true, false, true><<<dim3(1536 / 128, M_ROWS / 128), 256, 0, stream>>>(
        h, W1_t, b1, nullptr, ff, M_ROWS, 1536, 384);
    // 7. out += ff @ W2 + b2
    mfma_gemm<false, true, false><<<dim3(384 / 128, M_ROWS / 128), 256, 0, stream>>>(
        ff, W2_t, b2, out, out, M_ROWS, 384, 1536);
}

// Round 5
// 539.706 us; speedup vs baseline: 7.9270x; 1.2763x over previous
//
#include <hip/hip_runtime.h>
#include <hip/hip_bf16.h>

#define C_EMB 384
#define T_SEQ 256
#define B_BATCH 128
#define M_ROWS (B_BATCH * T_SEQ)   // 32768
#define QKV_LD 1152                // row stride of qkv buffer (bf16 now)

typedef __bf16 bf16_8 __attribute__((ext_vector_type(8)));
typedef float f32x4 __attribute__((ext_vector_type(4)));

// ---------------- Weight cast + transpose: Wt[n][k] = bf16(W[k][n]) ------------------
__global__ __launch_bounds__(256) void cast_transpose_kernel(const float* __restrict__ W,
                                                             __bf16* __restrict__ Wt,
                                                             int K, int N) {
    __shared__ float t[32][33];
    int k0 = blockIdx.y * 32, n0 = blockIdx.x * 32;
    int tx = threadIdx.x & 31, ty = threadIdx.x >> 5;  // ty: 0..7
#pragma unroll
    for (int i = 0; i < 4; ++i)
        t[ty + i * 8][tx] = W[(size_t)(k0 + ty + i * 8) * N + n0 + tx];
    __syncthreads();
#pragma unroll
    for (int i = 0; i < 4; ++i) {
        int n = ty + i * 8;
        Wt[(size_t)(n0 + n) * K + k0 + tx] = (__bf16)t[tx][n];
    }
}

// ---------------- LayerNorm: one block (384 threads) per row, bf16 out ----------------
__global__ __launch_bounds__(384) void ln_kernel(const float* __restrict__ x,
                                                 const float* __restrict__ g,
                                                 const float* __restrict__ bta,
                                                 __bf16* __restrict__ out) {
    int row = blockIdx.x;
    int c = threadIdx.x;
    float v = x[(size_t)row * C_EMB + c];

    __shared__ float red[6];
    float s = v;
#pragma unroll
    for (int o = 32; o; o >>= 1) s += __shfl_down(s, o);
    if ((c & 63) == 0) red[c >> 6] = s;
    __syncthreads();
    float mu = (red[0] + red[1] + red[2] + red[3] + red[4] + red[5]) * (1.0f / C_EMB);

    float d = v - mu;
    float s2 = d * d;
#pragma unroll
    for (int o = 32; o; o >>= 1) s2 += __shfl_down(s2, o);
    __syncthreads();
    if ((c & 63) == 0) red[c >> 6] = s2;
    __syncthreads();
    float var = (red[0] + red[1] + red[2] + red[3] + red[4] + red[5]) * (1.0f / C_EMB);

    out[(size_t)row * C_EMB + c] = (__bf16)(d * rsqrtf(var + 1e-5f) * g[c] + bta[c]);
}

// ---------------- bf16 MFMA GEMM core constants --------------------------------------
// 128x128 tile, 256 thr = 2x2 waves, each wave 4x4 of 16x16x32 mfma. BK=32.
// LDS row stride 40 bf16 (80 B): frag reads land 2-way max on banks (free per m136).
// __align__(16): staging uses 16-B ds ops (round-3 abort was missing this).
#define BK 32
#define LDSS 40

// out = A[M,K](lda) @ Bt[N,K](ldb)^T + bias (+relu)(+resid)
template <bool RELU, bool RESID, bool OUT_BF16>
__global__ __launch_bounds__(256) void mfma_gemm(const __bf16* __restrict__ A, int lda,
                                                 const __bf16* __restrict__ Bt, int ldb,
                                                 const float* __restrict__ bias,
                                                 const float* __restrict__ resid,
                                                 void* __restrict__ out_,
                                                 int N, int K) {
    __shared__ __align__(16) __bf16 As[128 * LDSS];
    __shared__ __align__(16) __bf16 Bs[128 * LDSS];

    int tid = threadIdx.x;
    int wave = tid >> 6, lane = tid & 63;
    int wr = wave >> 1, wc = wave & 1;
    int quad = lane >> 4, l16 = lane & 15;
    int bm = blockIdx.y * 128, bn = blockIdx.x * 128;

    f32x4 acc[4][4] = {};

    int c0 = tid, c1 = tid + 256;
    int ra0 = c0 >> 2, ka0 = (c0 & 3) * 8;
    int ra1 = c1 >> 2, ka1 = (c1 & 3) * 8;

    for (int k0 = 0; k0 < K; k0 += BK) {
        const __bf16* Ab = A + (size_t)bm * lda + k0;
        const __bf16* Bb = Bt + (size_t)bn * ldb + k0;
        float4 a0 = *reinterpret_cast<const float4*>(Ab + (size_t)ra0 * lda + ka0);
        float4 a1 = *reinterpret_cast<const float4*>(Ab + (size_t)ra1 * lda + ka1);
        float4 b0 = *reinterpret_cast<const float4*>(Bb + (size_t)ra0 * ldb + ka0);
        float4 b1 = *reinterpret_cast<const float4*>(Bb + (size_t)ra1 * ldb + ka1);
        *reinterpret_cast<float4*>(&As[ra0 * LDSS + ka0]) = a0;
        *reinterpret_cast<float4*>(&As[ra1 * LDSS + ka1]) = a1;
        *reinterpret_cast<float4*>(&Bs[ra0 * LDSS + ka0]) = b0;
        *reinterpret_cast<float4*>(&Bs[ra1 * LDSS + ka1]) = b1;
        __syncthreads();

        bf16_8 af[4], bf[4];
#pragma unroll
        for (int i = 0; i < 4; ++i)
            af[i] = *reinterpret_cast<const bf16_8*>(&As[(wr * 64 + i * 16 + l16) * LDSS + quad * 8]);
#pragma unroll
        for (int j = 0; j < 4; ++j)
            bf[j] = *reinterpret_cast<const bf16_8*>(&Bs[(wc * 64 + j * 16 + l16) * LDSS + quad * 8]);
#pragma unroll
        for (int i = 0; i < 4; ++i)
#pragma unroll
            for (int j = 0; j < 4; ++j)
                acc[i][j] = __builtin_amdgcn_mfma_f32_16x16x32_bf16(af[i], bf[j], acc[i][j], 0, 0, 0);
        __syncthreads();
    }

    // C/D layout: col = lane&15, row = quad*4 + r  [m89-verified]
#pragma unroll
    for (int i = 0; i < 4; ++i) {
#pragma unroll
        for (int r = 0; r < 4; ++r) {
            int m = bm + wr * 64 + i * 16 + quad * 4 + r;
#pragma unroll
            for (int j = 0; j < 4; ++j) {
                int n = bn + wc * 64 + j * 16 + l16;
                float v = acc[i][j][r] + bias[n];
                if (RELU) v = fmaxf(v, 0.0f);
                if (RESID) v += resid[(size_t)m * N + n];
                if (OUT_BF16)
                    ((__bf16*)out_)[(size_t)m * N + n] = (__bf16)v;
                else
                    ((float*)out_)[(size_t)m * N + n] = v;
            }
        }
    }
}

// ---------------- V transpose: Vt[b][c][s] = qkv[b][s][768+c] -------------------------
__global__ __launch_bounds__(256) void vt_kernel(const __bf16* __restrict__ qkv,
                                                 __bf16* __restrict__ Vt) {
    __shared__ __align__(16) __bf16 t[32][72];  // [s][c], pad to 72 (144 B rows)
    int b = blockIdx.z, c0 = blockIdx.x * 64, s0 = blockIdx.y * 32;
    int tid = threadIdx.x;

    int tx = tid & 7, ty = tid >> 3;  // load: ty = s (32 rows), tx = c-chunk (8 x 8)
    const __bf16* src = qkv + ((size_t)b * T_SEQ + s0 + ty) * QKV_LD + 768 + c0 + tx * 8;
    *reinterpret_cast<float4*>(&t[ty][tx * 8]) = *reinterpret_cast<const float4*>(src);
    __syncthreads();

    int sx = tid & 3, cy = tid >> 2;  // write: cy = c (64 rows), sx = s-chunk (4 x 8)
    __align__(16) __bf16 tmp[8];
#pragma unroll
    for (int j = 0; j < 8; ++j) tmp[j] = t[sx * 8 + j][cy];
    *reinterpret_cast<float4*>(&Vt[((size_t)b * C_EMB + c0 + cy) * T_SEQ + s0 + sx * 8]) =
        *reinterpret_cast<float4*>(tmp);
}

// ---------------- Attention pass 1: S = scale * Q @ K^T (MFMA, tri-tiles) -------------
// tiles (tm,tn): (0,0),(1,0),(1,1). Upper-tri entries of diagonal tiles are garbage;
// softmax masks them.
__global__ __launch_bounds__(256) void qk_mfma(const __bf16* __restrict__ qkv,
                                               float* __restrict__ S) {
    static const int TM[3] = {0, 1, 1};
    static const int TN[3] = {0, 0, 1};
    int b = blockIdx.y;
    int bm = TM[blockIdx.x] * 128, bn = TN[blockIdx.x] * 128;
    const __bf16* Ab0 = qkv + (size_t)b * T_SEQ * QKV_LD;  // Q rows
    const __bf16* Bb0 = Ab0 + 384;                          // K rows

    __shared__ __align__(16) __bf16 As[128 * LDSS];
    __shared__ __align__(16) __bf16 Bs[128 * LDSS];

    int tid = threadIdx.x;
    int wave = tid >> 6, lane = tid & 63;
    int wr = wave >> 1, wc = wave & 1;
    int quad = lane >> 4, l16 = lane & 15;

    f32x4 acc[4][4] = {};

    int c0 = tid, c1 = tid + 256;
    int ra0 = c0 >> 2, ka0 = (c0 & 3) * 8;
    int ra1 = c1 >> 2, ka1 = (c1 & 3) * 8;

    for (int k0 = 0; k0 < C_EMB; k0 += BK) {
        const __bf16* Ab = Ab0 + (size_t)bm * QKV_LD + k0;
        const __bf16* Bb = Bb0 + (size_t)bn * QKV_LD + k0;
        float4 a0 = *reinterpret_cast<const float4*>(Ab + (size_t)ra0 * QKV_LD + ka0);
        float4 a1 = *reinterpret_cast<const float4*>(Ab + (size_t)ra1 * QKV_LD + ka1);
        float4 b0 = *reinterpret_cast<const float4*>(Bb + (size_t)ra0 * QKV_LD + ka0);
        float4 b1 = *reinterpret_cast<const float4*>(Bb + (size_t)ra1 * QKV_LD + ka1);
        *reinterpret_cast<float4*>(&As[ra0 * LDSS + ka0]) = a0;
        *reinterpret_cast<float4*>(&As[ra1 * LDSS + ka1]) = a1;
        *reinterpret_cast<float4*>(&Bs[ra0 * LDSS + ka0]) = b0;
        *reinterpret_cast<float4*>(&Bs[ra1 * LDSS + ka1]) = b1;
        __syncthreads();

        bf16_8 af[4], bf[4];
#pragma unroll
        for (int i = 0; i < 4; ++i)
            af[i] = *reinterpret_cast<const bf16_8*>(&As[(wr * 64 + i * 16 + l16) * LDSS + quad * 8]);
#pragma unroll
        for (int j = 0; j < 4; ++j)
            bf[j] = *reinterpret_cast<const bf16_8*>(&Bs[(wc * 64 + j * 16 + l16) * LDSS + quad * 8]);
#pragma unroll
        for (int i = 0; i < 4; ++i)
#pragma unroll
            for (int j = 0; j < 4; ++j)
                acc[i][j] = __builtin_amdgcn_mfma_f32_16x16x32_bf16(af[i], bf[j], acc[i][j], 0, 0, 0);
        __syncthreads();
    }

    float* Sb = S + (size_t)b * T_SEQ * T_SEQ;
#pragma unroll
    for (int i = 0; i < 4; ++i) {
#pragma unroll
        for (int r = 0; r < 4; ++r) {
            int m = bm + wr * 64 + i * 16 + quad * 4 + r;
#pragma unroll
            for (int j = 0; j < 4; ++j) {
                int n = bn + wc * 64 + j * 16 + l16;
                Sb[(size_t)m * T_SEQ + n] = acc[i][j][r] * 0.05103103630798288f;  // 1/sqrt(384)
            }
        }
    }
}

// ---------------- Attention pass 2: causal softmax, fp32 S → bf16 P -------------------
__global__ __launch_bounds__(256) void softmax_kernel(const float* __restrict__ S,
                                                      __bf16* __restrict__ P) {
    int row = blockIdx.x;
    int t = row & (T_SEQ - 1);
    int tid = threadIdx.x;
    const float* Sr = S + (size_t)row * T_SEQ;

    __shared__ float red[4];
    float sc = (tid <= t) ? Sr[tid] : -INFINITY;

    float mx = sc;
#pragma unroll
    for (int o = 32; o; o >>= 1) mx = fmaxf(mx, __shfl_down(mx, o));
    if ((tid & 63) == 0) red[tid >> 6] = mx;
    __syncthreads();
    mx = fmaxf(fmaxf(red[0], red[1]), fmaxf(red[2], red[3]));

    float p = (tid <= t) ? __expf(sc - mx) : 0.0f;
    float sm = p;
#pragma unroll
    for (int o = 32; o; o >>= 1) sm += __shfl_down(sm, o);
    __syncthreads();
    if ((tid & 63) == 0) red[tid >> 6] = sm;
    __syncthreads();
    sm = red[0] + red[1] + red[2] + red[3];

    P[(size_t)row * T_SEQ + tid] = (__bf16)(p / sm);  // zeros for s > t
}

// ---------------- Attention pass 3: y = P @ V (MFMA, causal k-skip) -------------------
__global__ __launch_bounds__(256) void pv_mfma(const __bf16* __restrict__ P,
                                               const __bf16* __restrict__ Vt,
                                               __bf16* __restrict__ y) {
    int b = blockIdx.z;
    int bm = blockIdx.y * 128, bn = blockIdx.x * 128;  // bn over 384 channels (3 tiles)
    const __bf16* Ab0 = P + (size_t)b * T_SEQ * T_SEQ;       // lda = 256
    const __bf16* Bb0 = Vt + (size_t)b * C_EMB * T_SEQ;      // ldb = 256

    __shared__ __align__(16) __bf16 As[128 * LDSS];
    __shared__ __align__(16) __bf16 Bs[128 * LDSS];

    int tid = threadIdx.x;
    int wave = tid >> 6, lane = tid & 63;
    int wr = wave >> 1, wc = wave & 1;
    int quad = lane >> 4, l16 = lane & 15;

    f32x4 acc[4][4] = {};

    int c0 = tid, c1 = tid + 256;
    int ra0 = c0 >> 2, ka0 = (c0 & 3) * 8;
    int ra1 = c1 >> 2, ka1 = (c1 & 3) * 8;

    int kmax = bm + 128;  // rows m < bm+128 attend only to s <= m < kmax
    for (int k0 = 0; k0 < kmax; k0 += BK) {
        const __bf16* Ab = Ab0 + (size_t)bm * T_SEQ + k0;
        const __bf16* Bb = Bb0 + (size_t)bn * T_SEQ + k0;
        float4 a0 = *reinterpret_cast<const float4*>(Ab + (size_t)ra0 * T_SEQ + ka0);
        float4 a1 = *reinterpret_cast<const float4*>(Ab + (size_t)ra1 * T_SEQ + ka1);
        float4 b0 = *reinterpret_cast<const float4*>(Bb + (size_t)ra0 * T_SEQ + ka0);
        float4 b1 = *reinterpret_cast<const float4*>(Bb + (size_t)ra1 * T_SEQ + ka1);
        *reinterpret_cast<float4*>(&As[ra0 * LDSS + ka0]) = a0;
        *reinterpret_cast<float4*>(&As[ra1 * LDSS + ka1]) = a1;
        *reinterpret_cast<float4*>(&Bs[ra0 * LDSS + ka0]) = b0;
        *reinterpret_cast<float4*>(&Bs[ra1 * LDSS + ka1]) = b1;
        __syncthreads();

        bf16_8 af[4], bf[4];
#pragma unroll
        for (int i = 0; i < 4; ++i)
            af[i] = *reinterpret_cast<const bf16_8*>(&As[(wr * 64 + i * 16 + l16) * LDSS + quad * 8]);
#pragma unroll
        for (int j = 0; j < 4; ++j)
            bf[j] = *reinterpret_cast<const bf16_8*>(&Bs[(wc * 64 + j * 16 + l16) * LDSS + quad * 8]);
#pragma unroll
        for (int i = 0; i < 4; ++i)
#pragma unroll
            for (int j = 0; j < 4; ++j)
                acc[i][j] = __builtin_amdgcn_mfma_f32_16x16x32_bf16(af[i], bf[j], acc[i][j], 0, 0, 0);
        __syncthreads();
    }

#pragma unroll
    for (int i = 0; i < 4; ++i) {
#pragma unroll
        for (int r = 0; r < 4; ++r) {
            int m = bm + wr * 64 + i * 16 + quad * 4 + r;
#pragma unroll
            for (int j = 0; j < 4; ++j) {
                int n = bn + wc * 64 + j * 16 + l16;
                y[((size_t)b * T_SEQ + m) * C_EMB + n] = (__bf16)acc[i][j][r];
            }
        }
    }
}

extern "C" void kernel_launch(void* const* d_in, const int* in_sizes, int n_in,
                              void* d_out, int out_size, void* d_ws, size_t ws_size,
                              hipStream_t stream) {
    const float* x      = (const float*)d_in[0];
    const float* W_attn = (const float*)d_in[1];
    const float* b_attn = (const float*)d_in[2];
    const float* W_proj = (const float*)d_in[3];
    const float* b_proj = (const float*)d_in[4];
    const float* ln1_g  = (const float*)d_in[5];
    const float* ln1_b  = (const float*)d_in[6];
    const float* ln2_g  = (const float*)d_in[7];
    const float* ln2_b  = (const float*)d_in[8];
    const float* W1     = (const float*)d_in[9];
    const float* b1     = (const float*)d_in[10];
    const float* W2     = (const float*)d_in[11];
    const float* b2     = (const float*)d_in[12];
    float* out = (float*)d_out;

    // ---- workspace (205 MB total; ws >= 251.6 MB proven in round 0) ----
    // Wt's | h | yb | qkv | S | Pb | Vt ;  ff aliases dead qkv+S
    __bf16* Wattn_t = (__bf16*)d_ws;                            // [1152,384]
    __bf16* Wproj_t = Wattn_t + (size_t)1152 * 384;             // [384,384]
    __bf16* W1_t    = Wproj_t + (size_t)384 * 384;              // [1536,384]
    __bf16* W2_t    = W1_t + (size_t)1536 * 384;                // [384,1536]
    __bf16* h       = W2_t + (size_t)384 * 1536;                // [M,384] bf16
    __bf16* yb      = h + (size_t)M_ROWS * 384;                 // [M,384] bf16
    __bf16* qkv     = yb + (size_t)M_ROWS * 384;                // [M,1152] bf16
    float*  S       = (float*)(qkv + (size_t)M_ROWS * QKV_LD);  // [B,T,T] fp32
    __bf16* Pb      = (__bf16*)(S + (size_t)B_BATCH * T_SEQ * T_SEQ);  // [B,T,T] bf16
    __bf16* Vt      = Pb + (size_t)B_BATCH * T_SEQ * T_SEQ;     // [B,384,T] bf16
    __bf16* ff      = qkv;                                      // [M,1536] bf16 alias

    // 0. weights → bf16, transposed to [N,K]
    cast_transpose_kernel<<<dim3(1152 / 32, 384 / 32), 256, 0, stream>>>(W_attn, Wattn_t, 384, 1152);
    cast_transpose_kernel<<<dim3(384 / 32, 384 / 32), 256, 0, stream>>>(W_proj, Wproj_t, 384, 384);
    cast_transpose_kernel<<<dim3(1536 / 32, 384 / 32), 256, 0, stream>>>(W1, W1_t, 384, 1536);
    cast_transpose_kernel<<<dim3(384 / 32, 1536 / 32), 256, 0, stream>>>(W2, W2_t, 1536, 384);

    // 1. h = bf16(LN1(x))
    ln_kernel<<<M_ROWS, 384, 0, stream>>>(x, ln1_g, ln1_b, h);
    // 2. qkv = bf16(h @ W_attn + b_attn)
    mfma_gemm<false, false, true><<<dim3(1152 / 128, M_ROWS / 128), 256, 0, stream>>>(
        h, 384, Wattn_t, 384, b_attn, nullptr, qkv, 1152, 384);
    // 3. attention (bf16 MFMA core)
    vt_kernel<<<dim3(C_EMB / 64, T_SEQ / 32, B_BATCH), 256, 0, stream>>>(qkv, Vt);
    qk_mfma<<<dim3(3, B_BATCH), 256, 0, stream>>>(qkv, S);
    softmax_kernel<<<M_ROWS, 256, 0, stream>>>(S, Pb);
    pv_mfma<<<dim3(C_EMB / 128, T_SEQ / 128, B_BATCH), 256, 0, stream>>>(Pb, Vt, yb);
    // 4. out = x + yb @ W_proj + b_proj
    mfma_gemm<false, true, false><<<dim3(384 / 128, M_ROWS / 128), 256, 0, stream>>>(
        yb, 384, Wproj_t, 384, b_proj, x, out, 384, 384);
    // 5. h2 = bf16(LN2(out))
    ln_kernel<<<M_ROWS, 384, 0, stream>>>(out, ln2_g, ln2_b, h);
    // 6. ff = bf16(relu(h2 @ W1 + b1))
    mfma_gemm<true, false, true><<<dim3(1536 / 128, M_ROWS / 128), 256, 0, stream>>>(
        h, 384, W1_t, 384, b1, nullptr, ff, 1536, 384);
    // 7. out += ff @ W2 + b2
    mfma_gemm<false, true, false><<<dim3(384 / 128, M_ROWS / 128), 256, 0, stream>>>(
        ff, 1536, W2_t, 1536, b2, out, out, 384, 1536);
}

// Round 6
// 520.929 us; speedup vs baseline: 8.2127x; 1.0360x over previous
//
#include <hip/hip_runtime.h>
#include <hip/hip_bf16.h>

#define C_EMB 384
#define T_SEQ 256
#define B_BATCH 128
#define M_ROWS (B_BATCH * T_SEQ)   // 32768
#define QKV_LD 1152                // row stride of qkv buffer (bf16)
#define BK 32                      // K-tile (bf16 elems); row = 64 B, unpadded (m97 layout)

typedef __bf16 bf16_8 __attribute__((ext_vector_type(8)));
typedef float f32x4 __attribute__((ext_vector_type(4)));

// Async global->LDS 16-B copy. Dest is wave-uniform base + lane*16 (m104/m108):
// LDS layout must be contiguous in lane order -> unpadded BK=32 rows (4 lanes/row).
__device__ __forceinline__ void load16_lds(const __bf16* g, __bf16* l) {
    __builtin_amdgcn_global_load_lds(
        (const __attribute__((address_space(1))) unsigned int*)g,
        (__attribute__((address_space(3))) unsigned int*)l, 16, 0, 0);
}

// ---------------- Weight cast + transpose: Wt[n][k] = bf16(W[k][n]) ------------------
__global__ __launch_bounds__(256) void cast_transpose_kernel(const float* __restrict__ W,
                                                             __bf16* __restrict__ Wt,
                                                             int K, int N) {
    __shared__ float t[32][33];
    int k0 = blockIdx.y * 32, n0 = blockIdx.x * 32;
    int tx = threadIdx.x & 31, ty = threadIdx.x >> 5;
#pragma unroll
    for (int i = 0; i < 4; ++i)
        t[ty + i * 8][tx] = W[(size_t)(k0 + ty + i * 8) * N + n0 + tx];
    __syncthreads();
#pragma unroll
    for (int i = 0; i < 4; ++i) {
        int n = ty + i * 8;
        Wt[(size_t)(n0 + n) * K + k0 + tx] = (__bf16)t[tx][n];
    }
}

// ---------------- LayerNorm: one block (384 threads) per row, bf16 out ----------------
__global__ __launch_bounds__(384) void ln_kernel(const float* __restrict__ x,
                                                 const float* __restrict__ g,
                                                 const float* __restrict__ bta,
                                                 __bf16* __restrict__ out) {
    int row = blockIdx.x;
    int c = threadIdx.x;
    float v = x[(size_t)row * C_EMB + c];

    __shared__ float red[6];
    float s = v;
#pragma unroll
    for (int o = 32; o; o >>= 1) s += __shfl_down(s, o);
    if ((c & 63) == 0) red[c >> 6] = s;
    __syncthreads();
    float mu = (red[0] + red[1] + red[2] + red[3] + red[4] + red[5]) * (1.0f / C_EMB);

    float d = v - mu;
    float s2 = d * d;
#pragma unroll
    for (int o = 32; o; o >>= 1) s2 += __shfl_down(s2, o);
    __syncthreads();
    if ((c & 63) == 0) red[c >> 6] = s2;
    __syncthreads();
    float var = (red[0] + red[1] + red[2] + red[3] + red[4] + red[5]) * (1.0f / C_EMB);

    out[(size_t)row * C_EMB + c] = (__bf16)(d * rsqrtf(var + 1e-5f) * g[c] + bta[c]);
}

// ---------------- bf16 MFMA GEMM: out = A[M,K](lda) @ Bt[N,K](ldb)^T + bias ----------
// TM x 128 tile, 256 thr = 2x2 waves. TM=128: wave 64x64, acc 4x4. TM=64: wave 32x64,
// acc 2x4 (used for N=384 GEMMs: doubles grid -> 6 blocks/CU instead of 3).
// Staging: global_load_lds width=16, unpadded [row][BK] LDS (m97 pattern).
template <int TM, bool RELU, bool RESID, bool OUT_BF16>
__global__ __launch_bounds__(256) void mfma_gemm(const __bf16* __restrict__ A, int lda,
                                                 const __bf16* __restrict__ Bt, int ldb,
                                                 const float* __restrict__ bias,
                                                 const float* __restrict__ resid,
                                                 void* __restrict__ out_,
                                                 int N, int K) {
    constexpr int MI = TM / 32;      // acc m-tiles per wave
    constexpr int WROWS = TM / 2;    // wave quadrant rows
    __shared__ __align__(16) __bf16 As[TM * BK];
    __shared__ __align__(16) __bf16 Bs[128 * BK];

    int tid = threadIdx.x;
    int wave = tid >> 6, lane = tid & 63;
    int wr = wave >> 1, wc = wave & 1;
    int quad = lane >> 4, l16 = lane & 15;
    int bm = blockIdx.y * TM, bn = blockIdx.x * 128;
    int lrow = lane >> 2, lcol = (lane & 3) * 8;   // 16 rows x 4 chunks per wave-issue

    f32x4 acc[MI][4] = {};

    for (int k0 = 0; k0 < K; k0 += BK) {
        const __bf16* Ab = A + (size_t)bm * lda + k0;
        const __bf16* Bb = Bt + (size_t)bn * ldb + k0;
#pragma unroll
        for (int i = 0; i < TM / 64; ++i) {
            int r0 = (i * 4 + wave) * 16;
            load16_lds(Ab + (size_t)(r0 + lrow) * lda + lcol, &As[r0 * BK]);
        }
#pragma unroll
        for (int i = 0; i < 2; ++i) {
            int r0 = (i * 4 + wave) * 16;
            load16_lds(Bb + (size_t)(r0 + lrow) * ldb + lcol, &Bs[r0 * BK]);
        }
        __syncthreads();

        bf16_8 af[MI], bf[4];
#pragma unroll
        for (int i = 0; i < MI; ++i)
            af[i] = *reinterpret_cast<const bf16_8*>(&As[(wr * WROWS + i * 16 + l16) * BK + quad * 8]);
#pragma unroll
        for (int j = 0; j < 4; ++j)
            bf[j] = *reinterpret_cast<const bf16_8*>(&Bs[(wc * 64 + j * 16 + l16) * BK + quad * 8]);
#pragma unroll
        for (int i = 0; i < MI; ++i)
#pragma unroll
            for (int j = 0; j < 4; ++j)
                acc[i][j] = __builtin_amdgcn_mfma_f32_16x16x32_bf16(af[i], bf[j], acc[i][j], 0, 0, 0);
        __syncthreads();
    }

    // C/D layout: col = lane&15, row = quad*4 + r  [m89-verified]
#pragma unroll
    for (int i = 0; i < MI; ++i) {
#pragma unroll
        for (int r = 0; r < 4; ++r) {
            int m = bm + wr * WROWS + i * 16 + quad * 4 + r;
#pragma unroll
            for (int j = 0; j < 4; ++j) {
                int n = bn + wc * 64 + j * 16 + l16;
                float v = acc[i][j][r] + bias[n];
                if (RELU) v = fmaxf(v, 0.0f);
                if (RESID) v += resid[(size_t)m * N + n];
                if (OUT_BF16)
                    ((__bf16*)out_)[(size_t)m * N + n] = (__bf16)v;
                else
                    ((float*)out_)[(size_t)m * N + n] = v;
            }
        }
    }
}

// ---------------- V transpose: Vt[b][c][s] = qkv[b][s][768+c] -------------------------
__global__ __launch_bounds__(256) void vt_kernel(const __bf16* __restrict__ qkv,
                                                 __bf16* __restrict__ Vt) {
    __shared__ __align__(16) __bf16 t[32][72];
    int b = blockIdx.z, c0 = blockIdx.x * 64, s0 = blockIdx.y * 32;
    int tid = threadIdx.x;

    int tx = tid & 7, ty = tid >> 3;
    const __bf16* src = qkv + ((size_t)b * T_SEQ + s0 + ty) * QKV_LD + 768 + c0 + tx * 8;
    *reinterpret_cast<float4*>(&t[ty][tx * 8]) = *reinterpret_cast<const float4*>(src);
    __syncthreads();

    int sx = tid & 3, cy = tid >> 2;
    __align__(16) __bf16 tmp[8];
#pragma unroll
    for (int j = 0; j < 8; ++j) tmp[j] = t[sx * 8 + j][cy];
    *reinterpret_cast<float4*>(&Vt[((size_t)b * C_EMB + c0 + cy) * T_SEQ + s0 + sx * 8]) =
        *reinterpret_cast<float4*>(tmp);
}

// ---------------- Attention pass 1: S = scale * Q @ K^T (MFMA, tri-tiles) -------------
__global__ __launch_bounds__(256) void qk_mfma(const __bf16* __restrict__ qkv,
                                               float* __restrict__ S) {
    static const int TMt[3] = {0, 1, 1};
    static const int TNt[3] = {0, 0, 1};
    int b = blockIdx.y;
    int bm = TMt[blockIdx.x] * 128, bn = TNt[blockIdx.x] * 128;
    const __bf16* Ab0 = qkv + (size_t)b * T_SEQ * QKV_LD;
    const __bf16* Bb0 = Ab0 + 384;

    __shared__ __align__(16) __bf16 As[128 * BK];
    __shared__ __align__(16) __bf16 Bs[128 * BK];

    int tid = threadIdx.x;
    int wave = tid >> 6, lane = tid & 63;
    int wr = wave >> 1, wc = wave & 1;
    int quad = lane >> 4, l16 = lane & 15;
    int lrow = lane >> 2, lcol = (lane & 3) * 8;

    f32x4 acc[4][4] = {};

    for (int k0 = 0; k0 < C_EMB; k0 += BK) {
        const __bf16* Ab = Ab0 + (size_t)bm * QKV_LD + k0;
        const __bf16* Bb = Bb0 + (size_t)bn * QKV_LD + k0;
#pragma unroll
        for (int i = 0; i < 2; ++i) {
            int r0 = (i * 4 + wave) * 16;
            load16_lds(Ab + (size_t)(r0 + lrow) * QKV_LD + lcol, &As[r0 * BK]);
            load16_lds(Bb + (size_t)(r0 + lrow) * QKV_LD + lcol, &Bs[r0 * BK]);
        }
        __syncthreads();

        bf16_8 af[4], bf[4];
#pragma unroll
        for (int i = 0; i < 4; ++i)
            af[i] = *reinterpret_cast<const bf16_8*>(&As[(wr * 64 + i * 16 + l16) * BK + quad * 8]);
#pragma unroll
        for (int j = 0; j < 4; ++j)
            bf[j] = *reinterpret_cast<const bf16_8*>(&Bs[(wc * 64 + j * 16 + l16) * BK + quad * 8]);
#pragma unroll
        for (int i = 0; i < 4; ++i)
#pragma unroll
            for (int j = 0; j < 4; ++j)
                acc[i][j] = __builtin_amdgcn_mfma_f32_16x16x32_bf16(af[i], bf[j], acc[i][j], 0, 0, 0);
        __syncthreads();
    }

    float* Sb = S + (size_t)b * T_SEQ * T_SEQ;
#pragma unroll
    for (int i = 0; i < 4; ++i) {
#pragma unroll
        for (int r = 0; r < 4; ++r) {
            int m = bm + wr * 64 + i * 16 + quad * 4 + r;
#pragma unroll
            for (int j = 0; j < 4; ++j) {
                int n = bn + wc * 64 + j * 16 + l16;
                Sb[(size_t)m * T_SEQ + n] = acc[i][j][r] * 0.05103103630798288f;
            }
        }
    }
}

// ---------------- Attention pass 2: causal softmax, fp32 S → bf16 P -------------------
__global__ __launch_bounds__(256) void softmax_kernel(const float* __restrict__ S,
                                                      __bf16* __restrict__ P) {
    int row = blockIdx.x;
    int t = row & (T_SEQ - 1);
    int tid = threadIdx.x;
    const float* Sr = S + (size_t)row * T_SEQ;

    __shared__ float red[4];
    float sc = (tid <= t) ? Sr[tid] : -INFINITY;

    float mx = sc;
#pragma unroll
    for (int o = 32; o; o >>= 1) mx = fmaxf(mx, __shfl_down(mx, o));
    if ((tid & 63) == 0) red[tid >> 6] = mx;
    __syncthreads();
    mx = fmaxf(fmaxf(red[0], red[1]), fmaxf(red[2], red[3]));

    float p = (tid <= t) ? __expf(sc - mx) : 0.0f;
    float sm = p;
#pragma unroll
    for (int o = 32; o; o >>= 1) sm += __shfl_down(sm, o);
    __syncthreads();
    if ((tid & 63) == 0) red[tid >> 6] = sm;
    __syncthreads();
    sm = red[0] + red[1] + red[2] + red[3];

    P[(size_t)row * T_SEQ + tid] = (__bf16)(p / sm);
}

// ---------------- Attention pass 3: y = P @ V (MFMA, causal k-skip) -------------------
__global__ __launch_bounds__(256) void pv_mfma(const __bf16* __restrict__ P,
                                               const __bf16* __restrict__ Vt,
                                               __bf16* __restrict__ y) {
    int b = blockIdx.z;
    int bm = blockIdx.y * 128, bn = blockIdx.x * 128;
    const __bf16* Ab0 = P + (size_t)b * T_SEQ * T_SEQ;
    const __bf16* Bb0 = Vt + (size_t)b * C_EMB * T_SEQ;

    __shared__ __align__(16) __bf16 As[128 * BK];
    __shared__ __align__(16) __bf16 Bs[128 * BK];

    int tid = threadIdx.x;
    int wave = tid >> 6, lane = tid & 63;
    int wr = wave >> 1, wc = wave & 1;
    int quad = lane >> 4, l16 = lane & 15;
    int lrow = lane >> 2, lcol = (lane & 3) * 8;

    f32x4 acc[4][4] = {};

    int kmax = bm + 128;
    for (int k0 = 0; k0 < kmax; k0 += BK) {
        const __bf16* Ab = Ab0 + (size_t)bm * T_SEQ + k0;
        const __bf16* Bb = Bb0 + (size_t)bn * T_SEQ + k0;
#pragma unroll
        for (int i = 0; i < 2; ++i) {
            int r0 = (i * 4 + wave) * 16;
            load16_lds(Ab + (size_t)(r0 + lrow) * T_SEQ + lcol, &As[r0 * BK]);
            load16_lds(Bb + (size_t)(r0 + lrow) * T_SEQ + lcol, &Bs[r0 * BK]);
        }
        __syncthreads();

        bf16_8 af[4], bf[4];
#pragma unroll
        for (int i = 0; i < 4; ++i)
            af[i] = *reinterpret_cast<const bf16_8*>(&As[(wr * 64 + i * 16 + l16) * BK + quad * 8]);
#pragma unroll
        for (int j = 0; j < 4; ++j)
            bf[j] = *reinterpret_cast<const bf16_8*>(&Bs[(wc * 64 + j * 16 + l16) * BK + quad * 8]);
#pragma unroll
        for (int i = 0; i < 4; ++i)
#pragma unroll
            for (int j = 0; j < 4; ++j)
                acc[i][j] = __builtin_amdgcn_mfma_f32_16x16x32_bf16(af[i], bf[j], acc[i][j], 0, 0, 0);
        __syncthreads();
    }

#pragma unroll
    for (int i = 0; i < 4; ++i) {
#pragma unroll
        for (int r = 0; r < 4; ++r) {
            int m = bm + wr * 64 + i * 16 + quad * 4 + r;
#pragma unroll
            for (int j = 0; j < 4; ++j) {
                int n = bn + wc * 64 + j * 16 + l16;
                y[((size_t)b * T_SEQ + m) * C_EMB + n] = (__bf16)acc[i][j][r];
            }
        }
    }
}

extern "C" void kernel_launch(void* const* d_in, const int* in_sizes, int n_in,
                              void* d_out, int out_size, void* d_ws, size_t ws_size,
                              hipStream_t stream) {
    const float* x      = (const float*)d_in[0];
    const float* W_attn = (const float*)d_in[1];
    const float* b_attn = (const float*)d_in[2];
    const float* W_proj = (const float*)d_in[3];
    const float* b_proj = (const float*)d_in[4];
    const float* ln1_g  = (const float*)d_in[5];
    const float* ln1_b  = (const float*)d_in[6];
    const float* ln2_g  = (const float*)d_in[7];
    const float* ln2_b  = (const float*)d_in[8];
    const float* W1     = (const float*)d_in[9];
    const float* b1     = (const float*)d_in[10];
    const float* W2     = (const float*)d_in[11];
    const float* b2     = (const float*)d_in[12];
    float* out = (float*)d_out;

    // ---- workspace (205 MB; ws >= 251.6 MB proven) ----
    __bf16* Wattn_t = (__bf16*)d_ws;                            // [1152,384]
    __bf16* Wproj_t = Wattn_t + (size_t)1152 * 384;             // [384,384]
    __bf16* W1_t    = Wproj_t + (size_t)384 * 384;              // [1536,384]
    __bf16* W2_t    = W1_t + (size_t)1536 * 384;                // [384,1536]
    __bf16* h       = W2_t + (size_t)384 * 1536;                // [M,384] bf16
    __bf16* yb      = h + (size_t)M_ROWS * 384;                 // [M,384] bf16
    __bf16* qkv     = yb + (size_t)M_ROWS * 384;                // [M,1152] bf16
    float*  S       = (float*)(qkv + (size_t)M_ROWS * QKV_LD);  // [B,T,T] fp32
    __bf16* Pb      = (__bf16*)(S + (size_t)B_BATCH * T_SEQ * T_SEQ);  // [B,T,T] bf16
    __bf16* Vt      = Pb + (size_t)B_BATCH * T_SEQ * T_SEQ;     // [B,384,T] bf16
    __bf16* ff      = qkv;                                      // [M,1536] bf16 alias

    // 0. weights → bf16, transposed to [N,K]
    cast_transpose_kernel<<<dim3(1152 / 32, 384 / 32), 256, 0, stream>>>(W_attn, Wattn_t, 384, 1152);
    cast_transpose_kernel<<<dim3(384 / 32, 384 / 32), 256, 0, stream>>>(W_proj, Wproj_t, 384, 384);
    cast_transpose_kernel<<<dim3(1536 / 32, 384 / 32), 256, 0, stream>>>(W1, W1_t, 384, 1536);
    cast_transpose_kernel<<<dim3(384 / 32, 1536 / 32), 256, 0, stream>>>(W2, W2_t, 1536, 384);

    // 1. h = bf16(LN1(x))
    ln_kernel<<<M_ROWS, 384, 0, stream>>>(x, ln1_g, ln1_b, h);
    // 2. qkv = bf16(h @ W_attn + b_attn)
    mfma_gemm<128, false, false, true><<<dim3(1152 / 128, M_ROWS / 128), 256, 0, stream>>>(
        h, 384, Wattn_t, 384, b_attn, nullptr, qkv, 1152, 384);
    // 3. attention (bf16 MFMA core)
    vt_kernel<<<dim3(C_EMB / 64, T_SEQ / 32, B_BATCH), 256, 0, stream>>>(qkv, Vt);
    qk_mfma<<<dim3(3, B_BATCH), 256, 0, stream>>>(qkv, S);
    softmax_kernel<<<M_ROWS, 256, 0, stream>>>(S, Pb);
    pv_mfma<<<dim3(C_EMB / 128, T_SEQ / 128, B_BATCH), 256, 0, stream>>>(Pb, Vt, yb);
    // 4. out = x + yb @ W_proj + b_proj   (TM=64: 6 blocks/CU)
    mfma_gemm<64, false, true, false><<<dim3(384 / 128, M_ROWS / 64), 256, 0, stream>>>(
        yb, 384, Wproj_t, 384, b_proj, x, out, 384, 384);
    // 5. h2 = bf16(LN2(out))
    ln_kernel<<<M_ROWS, 384, 0, stream>>>(out, ln2_g, ln2_b, h);
    // 6. ff = bf16(relu(h2 @ W1 + b1))
    mfma_gemm<128, true, false, true><<<dim3(1536 / 128, M_ROWS / 128), 256, 0, stream>>>(
        h, 384, W1_t, 384, b1, nullptr, ff, 1536, 384);
    // 7. out += ff @ W2 + b2   (TM=64)
    mfma_gemm<64, false, true, false><<<dim3(384 / 128, M_ROWS / 64), 256, 0, stream>>>(
        ff, 1536, W2_t, 1536, b2, out, out, 384, 1536);
}

// Round 7
// 494.897 us; speedup vs baseline: 8.6447x; 1.0526x over previous
//
#include <hip/hip_runtime.h>
#include <hip/hip_bf16.h>

#define C_EMB 384
#define T_SEQ 256
#define B_BATCH 128
#define M_ROWS (B_BATCH * T_SEQ)   // 32768
#define QKV_LD 1152                // row stride of qkv buffer (bf16)
#define BK 64                      // K-tile = two 32-elem panels (each 64-B rows, m97 layout)

typedef __bf16 bf16_8 __attribute__((ext_vector_type(8)));
typedef float f32x4 __attribute__((ext_vector_type(4)));

// Async global->LDS 16-B copy. Dest is wave-uniform base + lane*16 (m104/m108).
__device__ __forceinline__ void load16_lds(const __bf16* g, __bf16* l) {
    __builtin_amdgcn_global_load_lds(
        (const __attribute__((address_space(1))) unsigned int*)g,
        (__attribute__((address_space(3))) unsigned int*)l, 16, 0, 0);
}

// ---------------- All-weights cast + transpose (single dispatch) ----------------------
// Wt[n][k] = bf16(W[k][n]) for the 4 weight matrices; block ranges select the matrix.
__global__ __launch_bounds__(256) void cast_all_kernel(const float* __restrict__ Wa,
                                                       const float* __restrict__ Wp,
                                                       const float* __restrict__ W1,
                                                       const float* __restrict__ W2,
                                                       __bf16* __restrict__ Wa_t,
                                                       __bf16* __restrict__ Wp_t,
                                                       __bf16* __restrict__ W1_t,
                                                       __bf16* __restrict__ W2_t) {
    int bid = blockIdx.x;
    const float* W; __bf16* Wt; int K, N, tx_n;
    // tile counts: Wa 36x12=432, Wp 12x12=144, W1 48x12=576, W2 12x48=576
    if (bid < 432)      { W = Wa; Wt = Wa_t; K = 384;  N = 1152; tx_n = 36; }
    else if (bid < 576) { bid -= 432; W = Wp; Wt = Wp_t; K = 384;  N = 384;  tx_n = 12; }
    else if (bid < 1152){ bid -= 576; W = W1; Wt = W1_t; K = 384;  N = 1536; tx_n = 48; }
    else                { bid -= 1152; W = W2; Wt = W2_t; K = 1536; N = 384;  tx_n = 12; }
    int n0 = (bid % tx_n) * 32, k0 = (bid / tx_n) * 32;

    __shared__ float t[32][33];
    int tx = threadIdx.x & 31, ty = threadIdx.x >> 5;
#pragma unroll
    for (int i = 0; i < 4; ++i)
        t[ty + i * 8][tx] = W[(size_t)(k0 + ty + i * 8) * N + n0 + tx];
    __syncthreads();
#pragma unroll
    for (int i = 0; i < 4; ++i) {
        int n = ty + i * 8;
        Wt[(size_t)(n0 + n) * K + k0 + tx] = (__bf16)t[tx][n];
    }
}

// ---------------- LayerNorm: one block (384 threads) per row, bf16 out ----------------
__global__ __launch_bounds__(384) void ln_kernel(const float* __restrict__ x,
                                                 const float* __restrict__ g,
                                                 const float* __restrict__ bta,
                                                 __bf16* __restrict__ out) {
    int row = blockIdx.x;
    int c = threadIdx.x;
    float v = x[(size_t)row * C_EMB + c];

    __shared__ float red[6];
    float s = v;
#pragma unroll
    for (int o = 32; o; o >>= 1) s += __shfl_down(s, o);
    if ((c & 63) == 0) red[c >> 6] = s;
    __syncthreads();
    float mu = (red[0] + red[1] + red[2] + red[3] + red[4] + red[5]) * (1.0f / C_EMB);

    float d = v - mu;
    float s2 = d * d;
#pragma unroll
    for (int o = 32; o; o >>= 1) s2 += __shfl_down(s2, o);
    __syncthreads();
    if ((c & 63) == 0) red[c >> 6] = s2;
    __syncthreads();
    float var = (red[0] + red[1] + red[2] + red[3] + red[4] + red[5]) * (1.0f / C_EMB);

    out[(size_t)row * C_EMB + c] = (__bf16)(d * rsqrtf(var + 1e-5f) * g[c] + bta[c]);
}

// ---------------- bf16 MFMA GEMM: out = A[M,K](lda) @ Bt[N,K](ldb)^T + bias ----------
// TM x 128 tile, 256 thr = 2x2 waves. BK=64 as two 32-col panels; each panel is the
// m97-verified unpadded 64-B-row LDS layout (bank geometry preserved), one barrier
// pair per 64 K — 2x MFMA per barrier vs round 6.
template <int TM, bool RELU, bool RESID, bool OUT_BF16>
__global__ __launch_bounds__(256) void mfma_gemm(const __bf16* __restrict__ A, int lda,
                                                 const __bf16* __restrict__ Bt, int ldb,
                                                 const float* __restrict__ bias,
                                                 const float* __restrict__ resid,
                                                 void* __restrict__ out_,
                                                 int N, int K) {
    constexpr int MI = TM / 32;      // acc m-tiles per wave
    constexpr int WROWS = TM / 2;    // wave quadrant rows
    __shared__ __align__(16) __bf16 As[2 * TM * 32];
    __shared__ __align__(16) __bf16 Bs[2 * 128 * 32];

    int tid = threadIdx.x;
    int wave = tid >> 6, lane = tid & 63;
    int wr = wave >> 1, wc = wave & 1;
    int quad = lane >> 4, l16 = lane & 15;
    int bm = blockIdx.y * TM, bn = blockIdx.x * 128;
    int lrow = lane >> 2, lcol = (lane & 3) * 8;   // 16 rows x 4 chunks per wave-issue

    f32x4 acc[MI][4] = {};

    for (int k0 = 0; k0 < K; k0 += BK) {
        const __bf16* Ab = A + (size_t)bm * lda + k0;
        const __bf16* Bb = Bt + (size_t)bn * ldb + k0;
#pragma unroll
        for (int p = 0; p < 2; ++p) {
#pragma unroll
            for (int i = 0; i < TM / 64; ++i) {
                int r0 = (i * 4 + wave) * 16;
                load16_lds(Ab + (size_t)(r0 + lrow) * lda + p * 32 + lcol,
                           &As[p * TM * 32 + r0 * 32]);
            }
#pragma unroll
            for (int i = 0; i < 2; ++i) {
                int r0 = (i * 4 + wave) * 16;
                load16_lds(Bb + (size_t)(r0 + lrow) * ldb + p * 32 + lcol,
                           &Bs[p * 128 * 32 + r0 * 32]);
            }
        }
        __syncthreads();

        bf16_8 af[MI][2], bf[4][2];
#pragma unroll
        for (int p = 0; p < 2; ++p) {
#pragma unroll
            for (int i = 0; i < MI; ++i)
                af[i][p] = *reinterpret_cast<const bf16_8*>(
                    &As[p * TM * 32 + (wr * WROWS + i * 16 + l16) * 32 + quad * 8]);
#pragma unroll
            for (int j = 0; j < 4; ++j)
                bf[j][p] = *reinterpret_cast<const bf16_8*>(
                    &Bs[p * 128 * 32 + (wc * 64 + j * 16 + l16) * 32 + quad * 8]);
        }
#pragma unroll
        for (int i = 0; i < MI; ++i)
#pragma unroll
            for (int j = 0; j < 4; ++j) {
                acc[i][j] = __builtin_amdgcn_mfma_f32_16x16x32_bf16(af[i][0], bf[j][0], acc[i][j], 0, 0, 0);
                acc[i][j] = __builtin_amdgcn_mfma_f32_16x16x32_bf16(af[i][1], bf[j][1], acc[i][j], 0, 0, 0);
            }
        __syncthreads();
    }

    // C/D layout: col = lane&15, row = quad*4 + r  [m89-verified]
#pragma unroll
    for (int i = 0; i < MI; ++i) {
#pragma unroll
        for (int r = 0; r < 4; ++r) {
            int m = bm + wr * WROWS + i * 16 + quad * 4 + r;
#pragma unroll
            for (int j = 0; j < 4; ++j) {
                int n = bn + wc * 64 + j * 16 + l16;
                float v = acc[i][j][r] + bias[n];
                if (RELU) v = fmaxf(v, 0.0f);
                if (RESID) v += resid[(size_t)m * N + n];
                if (OUT_BF16)
                    ((__bf16*)out_)[(size_t)m * N + n] = (__bf16)v;
                else
                    ((float*)out_)[(size_t)m * N + n] = v;
            }
        }
    }
}

// ---------------- V transpose: Vt[b][c][s] = qkv[b][s][768+c] -------------------------
__global__ __launch_bounds__(256) void vt_kernel(const __bf16* __restrict__ qkv,
                                                 __bf16* __restrict__ Vt) {
    __shared__ __align__(16) __bf16 t[32][72];
    int b = blockIdx.z, c0 = blockIdx.x * 64, s0 = blockIdx.y * 32;
    int tid = threadIdx.x;

    int tx = tid & 7, ty = tid >> 3;
    const __bf16* src = qkv + ((size_t)b * T_SEQ + s0 + ty) * QKV_LD + 768 + c0 + tx * 8;
    *reinterpret_cast<float4*>(&t[ty][tx * 8]) = *reinterpret_cast<const float4*>(src);
    __syncthreads();

    int sx = tid & 3, cy = tid >> 2;
    __align__(16) __bf16 tmp[8];
#pragma unroll
    for (int j = 0; j < 8; ++j) tmp[j] = t[sx * 8 + j][cy];
    *reinterpret_cast<float4*>(&Vt[((size_t)b * C_EMB + c0 + cy) * T_SEQ + s0 + sx * 8]) =
        *reinterpret_cast<float4*>(tmp);
}

// ---------------- Attention pass 1: S = scale * Q @ K^T (MFMA, tri-tiles) -------------
__global__ __launch_bounds__(256) void qk_mfma(const __bf16* __restrict__ qkv,
                                               float* __restrict__ S) {
    static const int TMt[3] = {0, 1, 1};
    static const int TNt[3] = {0, 0, 1};
    int b = blockIdx.y;
    int bm = TMt[blockIdx.x] * 128, bn = TNt[blockIdx.x] * 128;
    const __bf16* Ab0 = qkv + (size_t)b * T_SEQ * QKV_LD;
    const __bf16* Bb0 = Ab0 + 384;

    __shared__ __align__(16) __bf16 As[2 * 128 * 32];
    __shared__ __align__(16) __bf16 Bs[2 * 128 * 32];

    int tid = threadIdx.x;
    int wave = tid >> 6, lane = tid & 63;
    int wr = wave >> 1, wc = wave & 1;
    int quad = lane >> 4, l16 = lane & 15;
    int lrow = lane >> 2, lcol = (lane & 3) * 8;

    f32x4 acc[4][4] = {};

    for (int k0 = 0; k0 < C_EMB; k0 += BK) {
        const __bf16* Ab = Ab0 + (size_t)bm * QKV_LD + k0;
        const __bf16* Bb = Bb0 + (size_t)bn * QKV_LD + k0;
#pragma unroll
        for (int p = 0; p < 2; ++p)
#pragma unroll
            for (int i = 0; i < 2; ++i) {
                int r0 = (i * 4 + wave) * 16;
                load16_lds(Ab + (size_t)(r0 + lrow) * QKV_LD + p * 32 + lcol,
                           &As[p * 128 * 32 + r0 * 32]);
                load16_lds(Bb + (size_t)(r0 + lrow) * QKV_LD + p * 32 + lcol,
                           &Bs[p * 128 * 32 + r0 * 32]);
            }
        __syncthreads();

        bf16_8 af[4][2], bf[4][2];
#pragma unroll
        for (int p = 0; p < 2; ++p)
#pragma unroll
            for (int i = 0; i < 4; ++i) {
                af[i][p] = *reinterpret_cast<const bf16_8*>(
                    &As[p * 128 * 32 + (wr * 64 + i * 16 + l16) * 32 + quad * 8]);
                bf[i][p] = *reinterpret_cast<const bf16_8*>(
                    &Bs[p * 128 * 32 + (wc * 64 + i * 16 + l16) * 32 + quad * 8]);
            }
#pragma unroll
        for (int i = 0; i < 4; ++i)
#pragma unroll
            for (int j = 0; j < 4; ++j) {
                acc[i][j] = __builtin_amdgcn_mfma_f32_16x16x32_bf16(af[i][0], bf[j][0], acc[i][j], 0, 0, 0);
                acc[i][j] = __builtin_amdgcn_mfma_f32_16x16x32_bf16(af[i][1], bf[j][1], acc[i][j], 0, 0, 0);
            }
        __syncthreads();
    }

    float* Sb = S + (size_t)b * T_SEQ * T_SEQ;
#pragma unroll
    for (int i = 0; i < 4; ++i) {
#pragma unroll
        for (int r = 0; r < 4; ++r) {
            int m = bm + wr * 64 + i * 16 + quad * 4 + r;
#pragma unroll
            for (int j = 0; j < 4; ++j) {
                int n = bn + wc * 64 + j * 16 + l16;
                Sb[(size_t)m * T_SEQ + n] = acc[i][j][r] * 0.05103103630798288f;
            }
        }
    }
}

// ---------------- Attention pass 2: causal softmax, fp32 S → bf16 P -------------------
__global__ __launch_bounds__(256) void softmax_kernel(const float* __restrict__ S,
                                                      __bf16* __restrict__ P) {
    int row = blockIdx.x;
    int t = row & (T_SEQ - 1);
    int tid = threadIdx.x;
    const float* Sr = S + (size_t)row * T_SEQ;

    __shared__ float red[4];
    float sc = (tid <= t) ? Sr[tid] : -INFINITY;

    float mx = sc;
#pragma unroll
    for (int o = 32; o; o >>= 1) mx = fmaxf(mx, __shfl_down(mx, o));
    if ((tid & 63) == 0) red[tid >> 6] = mx;
    __syncthreads();
    mx = fmaxf(fmaxf(red[0], red[1]), fmaxf(red[2], red[3]));

    float p = (tid <= t) ? __expf(sc - mx) : 0.0f;
    float sm = p;
#pragma unroll
    for (int o = 32; o; o >>= 1) sm += __shfl_down(sm, o);
    __syncthreads();
    if ((tid & 63) == 0) red[tid >> 6] = sm;
    __syncthreads();
    sm = red[0] + red[1] + red[2] + red[3];

    P[(size_t)row * T_SEQ + tid] = (__bf16)(p / sm);
}

// ---------------- Attention pass 3: y = P @ V (MFMA, causal k-skip) -------------------
__global__ __launch_bounds__(256) void pv_mfma(const __bf16* __restrict__ P,
                                               const __bf16* __restrict__ Vt,
                                               __bf16* __restrict__ y) {
    int b = blockIdx.z;
    int bm = blockIdx.y * 128, bn = blockIdx.x * 128;
    const __bf16* Ab0 = P + (size_t)b * T_SEQ * T_SEQ;
    const __bf16* Bb0 = Vt + (size_t)b * C_EMB * T_SEQ;

    __shared__ __align__(16) __bf16 As[2 * 128 * 32];
    __shared__ __align__(16) __bf16 Bs[2 * 128 * 32];

    int tid = threadIdx.x;
    int wave = tid >> 6, lane = tid & 63;
    int wr = wave >> 1, wc = wave & 1;
    int quad = lane >> 4, l16 = lane & 15;
    int lrow = lane >> 2, lcol = (lane & 3) * 8;

    f32x4 acc[4][4] = {};

    int kmax = bm + 128;   // divisible by 64
    for (int k0 = 0; k0 < kmax; k0 += BK) {
        const __bf16* Ab = Ab0 + (size_t)bm * T_SEQ + k0;
        const __bf16* Bb = Bb0 + (size_t)bn * T_SEQ + k0;
#pragma unroll
        for (int p = 0; p < 2; ++p)
#pragma unroll
            for (int i = 0; i < 2; ++i) {
                int r0 = (i * 4 + wave) * 16;
                load16_lds(Ab + (size_t)(r0 + lrow) * T_SEQ + p * 32 + lcol,
                           &As[p * 128 * 32 + r0 * 32]);
                load16_lds(Bb + (size_t)(r0 + lrow) * T_SEQ + p * 32 + lcol,
                           &Bs[p * 128 * 32 + r0 * 32]);
            }
        __syncthreads();

        bf16_8 af[4][2], bf[4][2];
#pragma unroll
        for (int p = 0; p < 2; ++p)
#pragma unroll
            for (int i = 0; i < 4; ++i) {
                af[i][p] = *reinterpret_cast<const bf16_8*>(
                    &As[p * 128 * 32 + (wr * 64 + i * 16 + l16) * 32 + quad * 8]);
                bf[i][p] = *reinterpret_cast<const bf16_8*>(
                    &Bs[p * 128 * 32 + (wc * 64 + i * 16 + l16) * 32 + quad * 8]);
            }
#pragma unroll
        for (int i = 0; i < 4; ++i)
#pragma unroll
            for (int j = 0; j < 4; ++j) {
                acc[i][j] = __builtin_amdgcn_mfma_f32_16x16x32_bf16(af[i][0], bf[j][0], acc[i][j], 0, 0, 0);
                acc[i][j] = __builtin_amdgcn_mfma_f32_16x16x32_bf16(af[i][1], bf[j][1], acc[i][j], 0, 0, 0);
            }
        __syncthreads();
    }

#pragma unroll
    for (int i = 0; i < 4; ++i) {
#pragma unroll
        for (int r = 0; r < 4; ++r) {
            int m = bm + wr * 64 + i * 16 + quad * 4 + r;
#pragma unroll
            for (int j = 0; j < 4; ++j) {
                int n = bn + wc * 64 + j * 16 + l16;
                y[((size_t)b * T_SEQ + m) * C_EMB + n] = (__bf16)acc[i][j][r];
            }
        }
    }
}

extern "C" void kernel_launch(void* const* d_in, const int* in_sizes, int n_in,
                              void* d_out, int out_size, void* d_ws, size_t ws_size,
                              hipStream_t stream) {
    const float* x      = (const float*)d_in[0];
    const float* W_attn = (const float*)d_in[1];
    const float* b_attn = (const float*)d_in[2];
    const float* W_proj = (const float*)d_in[3];
    const float* b_proj = (const float*)d_in[4];
    const float* ln1_g  = (const float*)d_in[5];
    const float* ln1_b  = (const float*)d_in[6];
    const float* ln2_g  = (const float*)d_in[7];
    const float* ln2_b  = (const float*)d_in[8];
    const float* W1     = (const float*)d_in[9];
    const float* b1     = (const float*)d_in[10];
    const float* W2     = (const float*)d_in[11];
    const float* b2     = (const float*)d_in[12];
    float* out = (float*)d_out;

    // ---- workspace (205 MB; ws >= 251.6 MB proven) ----
    __bf16* Wattn_t = (__bf16*)d_ws;                            // [1152,384]
    __bf16* Wproj_t = Wattn_t + (size_t)1152 * 384;             // [384,384]
    __bf16* W1_t    = Wproj_t + (size_t)384 * 384;              // [1536,384]
    __bf16* W2_t    = W1_t + (size_t)1536 * 384;                // [384,1536]
    __bf16* h       = W2_t + (size_t)384 * 1536;                // [M,384] bf16
    __bf16* yb      = h + (size_t)M_ROWS * 384;                 // [M,384] bf16
    __bf16* qkv     = yb + (size_t)M_ROWS * 384;                // [M,1152] bf16
    float*  S       = (float*)(qkv + (size_t)M_ROWS * QKV_LD);  // [B,T,T] fp32
    __bf16* Pb      = (__bf16*)(S + (size_t)B_BATCH * T_SEQ * T_SEQ);  // [B,T,T] bf16
    __bf16* Vt      = Pb + (size_t)B_BATCH * T_SEQ * T_SEQ;     // [B,384,T] bf16
    __bf16* ff      = qkv;                                      // [M,1536] bf16 alias

    // 0. weights → bf16 [N,K], one dispatch (432+144+576+576 = 1728 tiles)
    cast_all_kernel<<<1728, 256, 0, stream>>>(W_attn, W_proj, W1, W2,
                                              Wattn_t, Wproj_t, W1_t, W2_t);

    // 1. h = bf16(LN1(x))
    ln_kernel<<<M_ROWS, 384, 0, stream>>>(x, ln1_g, ln1_b, h);
    // 2. qkv = bf16(h @ W_attn + b_attn)
    mfma_gemm<128, false, false, true><<<dim3(1152 / 128, M_ROWS / 128), 256, 0, stream>>>(
        h, 384, Wattn_t, 384, b_attn, nullptr, qkv, 1152, 384);
    // 3. attention (bf16 MFMA core)
    vt_kernel<<<dim3(C_EMB / 64, T_SEQ / 32, B_BATCH), 256, 0, stream>>>(qkv, Vt);
    qk_mfma<<<dim3(3, B_BATCH), 256, 0, stream>>>(qkv, S);
    softmax_kernel<<<M_ROWS, 256, 0, stream>>>(S, Pb);
    pv_mfma<<<dim3(C_EMB / 128, T_SEQ / 128, B_BATCH), 256, 0, stream>>>(Pb, Vt, yb);
    // 4. out = x + yb @ W_proj + b_proj   (TM=64: 6 blocks/CU)
    mfma_gemm<64, false, true, false><<<dim3(384 / 128, M_ROWS / 64), 256, 0, stream>>>(
        yb, 384, Wproj_t, 384, b_proj, x, out, 384, 384);
    // 5. h2 = bf16(LN2(out))
    ln_kernel<<<M_ROWS, 384, 0, stream>>>(out, ln2_g, ln2_b, h);
    // 6. ff = bf16(relu(h2 @ W1 + b1))
    mfma_gemm<128, true, false, true><<<dim3(1536 / 128, M_ROWS / 128), 256, 0, stream>>>(
        h, 384, W1_t, 384, b1, nullptr, ff, 1536, 384);
    // 7. out += ff @ W2 + b2   (TM=64)
    mfma_gemm<64, false, true, false><<<dim3(384 / 128, M_ROWS / 64), 256, 0, stream>>>(
        ff, 1536, W2_t, 1536, b2, out, out, 384, 1536);
}